// Round 9
// baseline (8297.769 us; speedup 1.0000x reference)
//
#include <hip/hip_runtime.h>
#include <stdint.h>
#include <stddef.h>

#define T_ 512
#define B_ 128
#define D_ 400
#define H_ 400
#define HP 416
#define GP 1664            // 4*HP (per-dir padded gate dim)
#define NW 3328            // both dirs stacked
#define K0P 448            // padded K for layer 0 GEMM
#define K12P 832           // padded K for layers 1,2 GEMM
#define NTILES 13          // h tiles of 32 per dir
#define NGRP 8             // batch groups of 16
#define REC_BLOCKS 208     // 2*8*13

// tagged h buffer: [16 cid][2 parity][16 batch][416 col] u32 {bf16 h | tag16<<16}
#define HBT_U32   ((size_t)16*2*16*416)
#define HBT_BYTES (HBT_U32*4)            // 851968

// Whh register-fragment blob: [2 dir][13 tile][4 gate][2 chalf][13 kk][64 lane][8]
#define WHHR_US8  ((size_t)2*13*4*2*13*64)
#define WHHR_BYTES (WHHR_US8*8*2)

typedef __attribute__((ext_vector_type(8))) __bf16 bf16x8;
typedef __attribute__((ext_vector_type(4))) float f32x4;
typedef __attribute__((ext_vector_type(8))) unsigned short us8;

__device__ __forceinline__ unsigned short f2bf(float f){
  unsigned u = __builtin_bit_cast(unsigned, f);
  u = (u + 0x7FFFu + ((u >> 16) & 1u)) >> 16;
  return (unsigned short)u;
}
__device__ __forceinline__ float bf2f(unsigned short s){
  unsigned u = ((unsigned)s) << 16;
  return __builtin_bit_cast(float, u);
}
__device__ __forceinline__ float sigm(float x){ return 1.f / (1.f + __expf(-x)); }
__device__ __forceinline__ float tanh_f(float x){
  float ax = fabsf(x);
  float e = __expf(-2.f * ax);
  float t = (1.f - e) / (1.f + e);
  return x < 0.f ? -t : t;
}
__device__ __forceinline__ void store_gx(float* p, float v){ *p = v; }
__device__ __forceinline__ void store_gx(unsigned short* p, float v){ *p = f2bf(v); }

// agent-scope relaxed atomics == MALL-coherent accesses, NO cache maintenance
__device__ __forceinline__ void h_store_u32(unsigned* p, unsigned v){
  __hip_atomic_store(p, v, __ATOMIC_RELAXED, __HIP_MEMORY_SCOPE_AGENT);
}
__device__ __forceinline__ unsigned long long h_load_u64(const unsigned long long* p){
  return __hip_atomic_load(p, __ATOMIC_RELAXED, __HIP_MEMORY_SCOPE_AGENT);
}

// ======================= prep kernels =======================
__global__ void k_conv_x0(const float* __restrict__ x, unsigned short* __restrict__ xa){
  const size_t i = (size_t)blockIdx.x*256 + threadIdx.x;
  if (i >= (size_t)T_*B_*K0P) return;
  const int k = (int)(i % K0P);
  const size_t tb = i / K0P;
  xa[i] = f2bf(k < D_ ? x[tb*D_ + k] : 0.f);
}

__global__ void k_prep_wih(const float* __restrict__ wf, const float* __restrict__ wb,
                           int K, int mode, unsigned short* __restrict__ dst){
  const size_t i = (size_t)blockIdx.x*256 + threadIdx.x;
  if (i >= (size_t)NW*K) return;
  const int k = (int)(i % K);
  const int n = (int)(i / K);
  const int d = n / GP, ng = n % GP, g = ng / HP, r = ng % HP;
  const float* Wsrc = d ? wb : wf;
  float v = 0.f;
  if (r < H_){
    if (mode == 0){                       // layer 0: K real 400
      if (k < D_) v = Wsrc[(size_t)(g*H_ + r)*D_ + k];
    } else {                              // layers 1,2: [fwd400|pad16|bwd400|pad16]
      int ks = (k < 400) ? k : ((k >= 416 && k < 816) ? (k - 16) : -1);
      if (ks >= 0) v = Wsrc[(size_t)(g*H_ + r)*800 + ks];
    }
  }
  dst[i] = f2bf(v);
}

// Whh -> per-(dir,tile,gate,chalf) MFMA B-fragments (R7-verified layout):
// lane l holds col c = tile*32 + ch*16 + (l&15), k = kk*32 + (l>>4)*8 + e.
__global__ void k_prep_whhR(const float* __restrict__ wf, const float* __restrict__ wb,
                            unsigned short* __restrict__ dst){
  const size_t i = (size_t)blockIdx.x*256 + threadIdx.x;
  if (i >= WHHR_US8) return;
  const int lane = (int)(i & 63);
  size_t q = i >> 6;
  const int kk = (int)(q % 13); q /= 13;
  const int ch = (int)(q % 2);  q /= 2;
  const int w  = (int)(q % 4);  q /= 4;
  const int tile = (int)(q % 13);
  const int dirx = (int)(q / 13);
  const int c  = tile*32 + ch*16 + (lane & 15);
  const int k0 = kk*32 + (lane >> 4)*8;
  const float* W = dirx ? wb : wf;
  unsigned short v[8];
  #pragma unroll
  for (int e = 0; e < 8; ++e){
    const int k = k0 + e;
    const float x = (c < H_ && k < H_) ? W[(size_t)(w*H_ + c)*H_ + k] : 0.f;
    v[e] = f2bf(x);
  }
  *(us8*)(dst + i*8) = *(const us8*)v;
}

__global__ void k_prep_bias(const float* __restrict__ bsf, const float* __restrict__ bsb,
                            float* __restrict__ dst){
  const int n = blockIdx.x*256 + threadIdx.x;
  if (n >= NW) return;
  const int d = n / GP, ng = n % GP, g = ng / HP, r = ng % HP;
  dst[n] = (r < H_) ? (d ? bsb : bsf)[g*H_ + r] : 0.f;
}

// ======================= gx GEMM (R4/R7 verbatim) =======================
template<typename GXT>
__global__ __launch_bounds__(256) void gemm_gx(
    const unsigned short* __restrict__ X, int lda, int K,
    const unsigned short* __restrict__ W,
    const float* __restrict__ bias,
    GXT* __restrict__ gx,
    const int* __restrict__ lens)
{
  const int t = blockIdx.y;
  if (t >= lens[0]) return;
  const int n0 = blockIdx.x * 128;
  __shared__ unsigned short As[128*64];
  __shared__ unsigned short Bs[128*64];
  const int tid = threadIdx.x;
  const int l = tid & 63;
  const int w = tid >> 6;
  const int wm = (w >> 1) * 64, wn = (w & 1) * 64;
  const int lr = l & 15, lk = l >> 4;
  f32x4 acc[4][4];
  #pragma unroll
  for (int i = 0; i < 4; ++i)
    #pragma unroll
    for (int j = 0; j < 4; ++j) acc[i][j] = (f32x4){0.f,0.f,0.f,0.f};

  const unsigned short* Xb = X + (size_t)t * B_ * lda;
  const int r_ = tid >> 3, s_ = (tid & 7) * 8;

  for (int k0 = 0; k0 < K; k0 += 64){
    us8 va[4], vb[4];
    #pragma unroll
    for (int i = 0; i < 4; ++i){
      const int r = i*32 + r_;
      va[i] = *(const us8*)(Xb + (size_t)r*lda + k0 + s_);
      vb[i] = *(const us8*)(W  + (size_t)(n0 + r)*K + k0 + s_);
    }
    __syncthreads();
    #pragma unroll
    for (int i = 0; i < 4; ++i){
      const int r = i*32 + r_;
      *(us8*)&As[r*64 + s_] = va[i];
      *(us8*)&Bs[r*64 + s_] = vb[i];
    }
    __syncthreads();
    #pragma unroll
    for (int kk = 0; kk < 2; ++kk){
      bf16x8 af[4], bfr[4];
      #pragma unroll
      for (int mi = 0; mi < 4; ++mi)
        af[mi] = __builtin_bit_cast(bf16x8, *(const us8*)&As[(wm + mi*16 + lr)*64 + kk*32 + lk*8]);
      #pragma unroll
      for (int ni = 0; ni < 4; ++ni)
        bfr[ni] = __builtin_bit_cast(bf16x8, *(const us8*)&Bs[(wn + ni*16 + lr)*64 + kk*32 + lk*8]);
      #pragma unroll
      for (int mi = 0; mi < 4; ++mi)
        #pragma unroll
        for (int ni = 0; ni < 4; ++ni)
          acc[mi][ni] = __builtin_amdgcn_mfma_f32_16x16x32_bf16(af[mi], bfr[ni], acc[mi][ni], 0, 0, 0);
    }
  }
  #pragma unroll
  for (int ni = 0; ni < 4; ++ni){
    const int col = n0 + wn + ni*16 + lr;
    const float bv = bias[col];
    #pragma unroll
    for (int mi = 0; mi < 4; ++mi){
      #pragma unroll
      for (int r = 0; r < 4; ++r){
        const int b = wm + mi*16 + lk*4 + r;
        store_gx(gx + ((size_t)t*B_ + b)*NW + col, acc[mi][ni][r] + bv);
      }
    }
  }
}

// ======================= recurrent (2-wave in-lane gates; NORMAL launch) =
// grid: 208 blocks = dir(2) x group(8 of 16 batches) x htile(13 of 32 cols)
// 128 threads = 2 waves; wave cf owns cols tile*32+cf*16..+16 for ALL 4
// gates (52 B-fragments = 208 VGPR, loop-invariant). All 4 gate accs for a
// (batch,col) land in ONE lane -> no gate exchange, cell fully in-register.
// h slots: per-col u32 {bf16 h | step-tag16 << 16} via MALL relaxed atomics.
// NOTE: launched as a REGULAR kernel. Co-residency by capacity arithmetic:
// 208 blocks x 2 waves at 1 wave/SIMD -> >=2 blocks/CU capacity = 512 >= 208.
// (Cooperative launch silently rejects >256-VGPR kernels — R6/R8 evidence.)
template<typename GXT, bool LAST>
__global__ __launch_bounds__(128, 1) void lstm_rec(
    const GXT* __restrict__ gx,
    const unsigned short* __restrict__ whhR,   // [2][13][4][2][13][64][8] bf16
    const int* __restrict__ lens,
    unsigned int* hbt,                         // tagged h (host-zeroed)
    unsigned short* __restrict__ xn,           // [T][128][832] bf16 (or unused)
    float* __restrict__ out)                   // [T][128][800] f32 (or unused)
{
  __shared__ unsigned short HS[16*424];        // 13568 B
  __shared__ float GXS[16*132];                // 8448 B

  const int tid = threadIdx.x;
  const int cf = tid >> 6, l = tid & 63;
  const int li = l & 15, lq = l >> 4;
  const int bid = blockIdx.x;
  const int dir  = bid / 104;
  const int rem  = bid % 104;
  const int grp  = rem / NTILES;
  const int tile = rem % NTILES;
  const int cid = dir*NGRP + grp;

  // Whh B-fragments (all 4 gates, own col-half) -> 208 VGPRs
  us8 Bf[52];
  #pragma unroll
  for (int g = 0; g < 4; ++g){
    const unsigned short* bs =
        whhR + ((size_t)(((dir*13 + tile)*4 + g)*2 + cf)*13*64 + l)*8;
    #pragma unroll
    for (int kk = 0; kk < 13; ++kk)
      Bf[g*13 + kk] = *(const us8*)(bs + (size_t)kk*512);
  }
  // precompute per-thread HS byte offsets for the 26 staged u64 lines
  unsigned hsOff[26];
  #pragma unroll
  for (int j = 0; j < 26; ++j){
    const int idx = j*128 + tid;          // [0, 3328) over [16 b][208 colpair]
    const int b = idx / 208, cp = idx % 208;
    hsOff[j] = (unsigned)(b*424 + 2*cp);  // in shorts
  }

  const int grp_len = lens[grp*16];
  int len_r[4];
  #pragma unroll
  for (int r = 0; r < 4; ++r) len_r[r] = lens[grp*16 + lq*4 + r];
  float cs[4] = {0.f,0.f,0.f,0.f}, hs[4] = {0.f,0.f,0.f,0.f};
  __syncthreads();

  int s_a = 0;
  const int pb = tid >> 3, q2 = tid & 7;       // gx->GXS mapping
  const int qg = q2 >> 1, qh = (q2 & 1)*16;
  const int myc = tile*32 + cf*16 + li;        // this lane's cell col

  for (int s = 0; s < T_; ++s){
    const int t = dir ? (T_ - 1 - s) : s;
    if (t >= grp_len) continue;                // whole group idle: uniform skip

    // ---- gx loads (16 contiguous f32 per thread; in flight during tag-wait)
    f32x4 gv[4];
    {
      const size_t goff = ((size_t)t*B_ + grp*16 + pb)*NW
                        + (size_t)dir*GP + qg*HP + tile*32 + qh;
      if constexpr (sizeof(GXT) == 4){
        const float* fp = (const float*)gx + goff;
        #pragma unroll
        for (int u = 0; u < 4; ++u) gv[u] = *(const f32x4*)(fp + u*4);
      } else {
        const unsigned short* up = (const unsigned short*)gx + goff;
        us8 a0 = *(const us8*)up, a1 = *(const us8*)(up + 8);
        #pragma unroll
        for (int e = 0; e < 4; ++e){
          gv[0][e] = bf2f(a0[e]);   gv[1][e] = bf2f(a0[e+4]);
          gv[2][e] = bf2f(a1[e]);   gv[3][e] = bf2f(a1[e+4]);
        }
      }
    }

    // ---- stage h (16x416 cols) -> LDS with per-u32 tag validation ----
    {
      const unsigned rtag = (unsigned)(s_a & 0xFFFF);
      const unsigned long long* hb = (const unsigned long long*)
          (hbt + (size_t)(cid*2 + (s_a & 1))*16*416);
      unsigned long long v[26];
      #pragma unroll
      for (int j = 0; j < 26; ++j)
        v[j] = h_load_u64(hb + j*128 + tid);
      unsigned stale = 0;
      #pragma unroll
      for (int j = 0; j < 26; ++j){
        const unsigned tl = ((unsigned)(v[j] >> 16)) & 0xFFFFu;
        const unsigned th = (unsigned)(v[j] >> 48);
        if ((tl != rtag) | (th != rtag)) stale |= 1u << j;
      }
      while (stale){
        const unsigned m = stale;
        #pragma unroll
        for (int j = 0; j < 26; ++j)
          if (m & (1u << j)) v[j] = h_load_u64(hb + j*128 + tid);
        #pragma unroll
        for (int j = 0; j < 26; ++j){
          if (m & (1u << j)){
            const unsigned tl = ((unsigned)(v[j] >> 16)) & 0xFFFFu;
            const unsigned th = (unsigned)(v[j] >> 48);
            if ((tl == rtag) & (th == rtag)) stale &= ~(1u << j);
          }
        }
      }
      #pragma unroll
      for (int j = 0; j < 26; ++j){
        const unsigned pk = ((unsigned)v[j] & 0xFFFFu)
                          | (((unsigned)(v[j] >> 32) & 0xFFFFu) << 16);
        *(unsigned*)&HS[hsOff[j]] = pk;
      }
    }
    // ---- gx -> GXS (piggybacks on staging barrier) ----
    {
      float* gp = &GXS[pb*132 + qg*32 + qh];
      *(f32x4*)gp        = gv[0];
      *(f32x4*)(gp + 4)  = gv[1];
      *(f32x4*)(gp + 8)  = gv[2];
      *(f32x4*)(gp + 12) = gv[3];
    }
    __syncthreads();

    // ---- 52 MFMAs: all 4 gates for own col-half ----
    f32x4 acc[4];
    #pragma unroll
    for (int g = 0; g < 4; ++g) acc[g] = (f32x4){0.f,0.f,0.f,0.f};
    {
      const int ab = li*424 + lq*8;
      #pragma unroll
      for (int kk = 0; kk < 13; ++kk){
        const bf16x8 av = __builtin_bit_cast(bf16x8, *(const us8*)&HS[ab + kk*32]);
        acc[0] = __builtin_amdgcn_mfma_f32_16x16x32_bf16(av, Bf[     kk], acc[0], 0, 0, 0);
        acc[1] = __builtin_amdgcn_mfma_f32_16x16x32_bf16(av, Bf[13 + kk], acc[1], 0, 0, 0);
        acc[2] = __builtin_amdgcn_mfma_f32_16x16x32_bf16(av, Bf[26 + kk], acc[2], 0, 0, 0);
        acc[3] = __builtin_amdgcn_mfma_f32_16x16x32_bf16(av, Bf[39 + kk], acc[3], 0, 0, 0);
      }
    }

    // ---- cell (fully in-lane) + tagged publish ----
    unsigned* hbW = hbt + (size_t)(cid*2 + ((s_a + 1) & 1))*16*416;
    const unsigned tagw = ((unsigned)((s_a + 1) & 0xFFFF)) << 16;
    #pragma unroll
    for (int r = 0; r < 4; ++r){
      const int bb = lq*4 + r;
      const float gi = acc[0][r] + GXS[bb*132 +        cf*16 + li];
      const float gf = acc[1][r] + GXS[bb*132 +  32 + cf*16 + li];
      const float gg = acc[2][r] + GXS[bb*132 +  64 + cf*16 + li];
      const float go = acc[3][r] + GXS[bb*132 +  96 + cf*16 + li];
      const float cn = sigm(gf)*cs[r] + sigm(gi)*tanh_f(gg);
      const float hn = sigm(go) * tanh_f(cn);
      if (t < len_r[r]){ cs[r] = cn; hs[r] = hn; }
      h_store_u32(hbW + (size_t)bb*416 + myc, (unsigned)f2bf(hs[r]) | tagw);
    }
    // ---- layer outputs (after publish) ----
    #pragma unroll
    for (int r = 0; r < 4; ++r){
      if (t < len_r[r]){
        const int bg = grp*16 + lq*4 + r;
        if constexpr (LAST){
          if (myc < H_) out[((size_t)t*B_ + bg)*800 + dir*H_ + myc] = hs[r];
        } else {
          xn[((size_t)t*B_ + bg)*832 + (size_t)dir*HP + myc] = f2bf(hs[r]);
        }
      }
    }
    __syncthreads();                           // HS/GXS reuse protection
    ++s_a;
  }
}

// ======================= host side =======================
template<typename GXT>
static void run_all(void* const* din, float* out, char* ws, hipStream_t stream)
{
  const float* x      = (const float*)din[0];
  const int* lens     = (const int*)din[1];
  const float* wihf0  = (const float*)din[2];
  const float* wihf12 = (const float*)din[3];
  const float* whhf   = (const float*)din[4];
  const float* bsf    = (const float*)din[5];
  const float* wihb0  = (const float*)din[6];
  const float* wihb12 = (const float*)din[7];
  const float* whhb   = (const float*)din[8];
  const float* bsb    = (const float*)din[9];

  char* p = ws;
  auto alloc = [&](size_t n){ char* r = p; p += (n + 255) & ~(size_t)255; return r; };
  GXT* gx            = (GXT*)alloc((size_t)T_*B_*NW*sizeof(GXT));
  unsigned short* xA = (unsigned short*)alloc((size_t)T_*B_*832*2);
  unsigned short* xB = (unsigned short*)alloc((size_t)T_*B_*832*2);
  unsigned short* wihp = (unsigned short*)alloc((size_t)NW*K12P*2);
  unsigned short* whhR = (unsigned short*)alloc(WHHR_BYTES);
  float* biasp       = (float*)alloc((size_t)NW*4);
  unsigned int* hbt  = (unsigned int*)alloc(HBT_BYTES);

  hipMemsetAsync(out, 0, (size_t)T_*B_*800*4, stream);
  {
    size_t n = (size_t)T_*B_*K0P;
    k_conv_x0<<<dim3((unsigned)((n+255)/256)), dim3(256), 0, stream>>>(x, xA);
  }

  const unsigned short* xin[3] = {xA, xB, xA};
  unsigned short* xout[3] = {xB, xA, nullptr};
  const int ldas[3] = {K0P, 832, 832};
  const int Ks[3]   = {K0P, K12P, K12P};

  for (int lyr = 0; lyr < 3; ++lyr){
    const float* wf = (lyr == 0) ? wihf0 : wihf12 + (size_t)(lyr-1)*1600*800;
    const float* wb = (lyr == 0) ? wihb0 : wihb12 + (size_t)(lyr-1)*1600*800;
    {
      size_t n = (size_t)NW*Ks[lyr];
      k_prep_wih<<<dim3((unsigned)((n+255)/256)), dim3(256), 0, stream>>>(
          wf, wb, Ks[lyr], lyr ? 1 : 0, wihp);
    }
    k_prep_bias<<<dim3((NW+255)/256), dim3(256), 0, stream>>>(
        bsf + (size_t)lyr*1600, bsb + (size_t)lyr*1600, biasp);
    gemm_gx<GXT><<<dim3(26, 512), dim3(256), 0, stream>>>(
        xin[lyr], ldas[lyr], Ks[lyr], wihp, biasp, gx, lens);
    {
      size_t n = WHHR_US8;
      k_prep_whhR<<<dim3((unsigned)((n+255)/256)), dim3(256), 0, stream>>>(
          whhf + (size_t)lyr*1600*400, whhb + (size_t)lyr*1600*400, whhR);
    }
    hipMemsetAsync(hbt, 0, HBT_BYTES, stream);

    if (lyr < 2)
      lstm_rec<GXT,false><<<dim3(REC_BLOCKS), dim3(128), 0, stream>>>(
          gx, whhR, lens, hbt, xout[lyr], out);
    else
      lstm_rec<GXT,true><<<dim3(REC_BLOCKS), dim3(128), 0, stream>>>(
          gx, whhR, lens, hbt, nullptr, out);
  }
}

extern "C" void kernel_launch(void* const* d_in, const int* in_sizes, int n_in,
                              void* d_out, int out_size, void* d_ws, size_t ws_size,
                              hipStream_t stream)
{
  (void)in_sizes; (void)n_in; (void)out_size;
  auto align = [](size_t n){ return (n + 255) & ~(size_t)255; };
  const size_t fixed =
      align((size_t)T_*B_*832*2) * 2 +
      align((size_t)NW*K12P*2) +
      align(WHHR_BYTES) +
      align((size_t)NW*4) +
      align(HBT_BYTES);
  const size_t need32 = align((size_t)T_*B_*NW*4) + fixed;
  const size_t need16 = align((size_t)T_*B_*NW*2) + fixed;

  if (ws_size >= need32)
    run_all<float>(d_in, (float*)d_out, (char*)d_ws, stream);
  else if (ws_size >= need16)
    run_all<unsigned short>(d_in, (float*)d_out, (char*)d_ws, stream);
  else
    hipMemsetAsync(d_out, 0, (size_t)T_*B_*800*4, stream);
}

// Round 10
// 6612.115 us; speedup vs baseline: 1.2549x; 1.2549x over previous
//
#include <hip/hip_runtime.h>
#include <stdint.h>
#include <stddef.h>

#define T_ 512
#define B_ 128
#define D_ 400
#define H_ 400
#define HP 416
#define GP 1664            // 4*HP (per-dir padded gate dim)
#define NW 3328            // both dirs stacked
#define K0P 448            // padded K for layer 0 GEMM
#define K12P 832           // padded K for layers 1,2 GEMM
#define NTILES 13          // h tiles of 32 per dir
#define NGRP 8             // batch groups of 16
#define REC_BLOCKS 208     // 2*8*13
#define PAIRS 208          // 416 cols / 2 per batch row (u64 slots)

// GC float stride
#define GC_FSTRIDE 576     // 16*36

// tagged h buffer: [16 cid][2 parity][16 batch][208 pair] u64
#define HBT_U64   ((size_t)16*2*16*PAIRS)
#define HBT_BYTES (HBT_U64*8)

// Whh register-fragment blob: [2 dir][13 tile][4 gate][2 chalf][13 kk][64 lane][8]
#define WHHR_US8  ((size_t)2*13*4*2*13*64)
#define WHHR_BYTES (WHHR_US8*8*2)

typedef __attribute__((ext_vector_type(8))) __bf16 bf16x8;
typedef __attribute__((ext_vector_type(4))) float f32x4;
typedef __attribute__((ext_vector_type(8))) unsigned short us8;

__device__ __forceinline__ unsigned short f2bf(float f){
  unsigned u = __builtin_bit_cast(unsigned, f);
  u = (u + 0x7FFFu + ((u >> 16) & 1u)) >> 16;
  return (unsigned short)u;
}
__device__ __forceinline__ float bf2f(unsigned short s){
  unsigned u = ((unsigned)s) << 16;
  return __builtin_bit_cast(float, u);
}
__device__ __forceinline__ float sigm(float x){ return 1.f / (1.f + __expf(-x)); }
__device__ __forceinline__ float tanh_f(float x){
  float ax = fabsf(x);
  float e = __expf(-2.f * ax);
  float t = (1.f - e) / (1.f + e);
  return x < 0.f ? -t : t;
}
__device__ __forceinline__ void store_gx(float* p, float v){ *p = v; }
__device__ __forceinline__ void store_gx(unsigned short* p, float v){ *p = f2bf(v); }

// agent-scope relaxed atomics == MALL-coherent accesses, NO cache maintenance
__device__ __forceinline__ void h_store_u64(unsigned long long* p, unsigned long long v){
  __hip_atomic_store(p, v, __ATOMIC_RELAXED, __HIP_MEMORY_SCOPE_AGENT);
}
__device__ __forceinline__ unsigned long long h_load_u64(const unsigned long long* p){
  return __hip_atomic_load(p, __ATOMIC_RELAXED, __HIP_MEMORY_SCOPE_AGENT);
}

// ======================= prep kernels =======================
__global__ void k_conv_x0(const float* __restrict__ x, unsigned short* __restrict__ xa){
  const size_t i = (size_t)blockIdx.x*256 + threadIdx.x;
  if (i >= (size_t)T_*B_*K0P) return;
  const int k = (int)(i % K0P);
  const size_t tb = i / K0P;
  xa[i] = f2bf(k < D_ ? x[tb*D_ + k] : 0.f);
}

__global__ void k_prep_wih(const float* __restrict__ wf, const float* __restrict__ wb,
                           int K, int mode, unsigned short* __restrict__ dst){
  const size_t i = (size_t)blockIdx.x*256 + threadIdx.x;
  if (i >= (size_t)NW*K) return;
  const int k = (int)(i % K);
  const int n = (int)(i / K);
  const int d = n / GP, ng = n % GP, g = ng / HP, r = ng % HP;
  const float* Wsrc = d ? wb : wf;
  float v = 0.f;
  if (r < H_){
    if (mode == 0){                       // layer 0: K real 400
      if (k < D_) v = Wsrc[(size_t)(g*H_ + r)*D_ + k];
    } else {                              // layers 1,2: [fwd400|pad16|bwd400|pad16]
      int ks = (k < 400) ? k : ((k >= 416 && k < 816) ? (k - 16) : -1);
      if (ks >= 0) v = Wsrc[(size_t)(g*H_ + r)*800 + ks];
    }
  }
  dst[i] = f2bf(v);
}

// Whh -> per-(dir,tile,gate,chalf) MFMA B-fragments (R7-verified layout):
// lane l holds col c = tile*32 + ch*16 + (l&15), k = kk*32 + (l>>4)*8 + e.
__global__ void k_prep_whhR(const float* __restrict__ wf, const float* __restrict__ wb,
                            unsigned short* __restrict__ dst){
  const size_t i = (size_t)blockIdx.x*256 + threadIdx.x;
  if (i >= WHHR_US8) return;
  const int lane = (int)(i & 63);
  size_t q = i >> 6;
  const int kk = (int)(q % 13); q /= 13;
  const int ch = (int)(q % 2);  q /= 2;
  const int w  = (int)(q % 4);  q /= 4;
  const int tile = (int)(q % 13);
  const int dirx = (int)(q / 13);
  const int c  = tile*32 + ch*16 + (lane & 15);
  const int k0 = kk*32 + (lane >> 4)*8;
  const float* W = dirx ? wb : wf;
  unsigned short v[8];
  #pragma unroll
  for (int e = 0; e < 8; ++e){
    const int k = k0 + e;
    const float x = (c < H_ && k < H_) ? W[(size_t)(w*H_ + c)*H_ + k] : 0.f;
    v[e] = f2bf(x);
  }
  *(us8*)(dst + i*8) = *(const us8*)v;
}

__global__ void k_prep_bias(const float* __restrict__ bsf, const float* __restrict__ bsb,
                            float* __restrict__ dst){
  const int n = blockIdx.x*256 + threadIdx.x;
  if (n >= NW) return;
  const int d = n / GP, ng = n % GP, g = ng / HP, r = ng % HP;
  dst[n] = (r < H_) ? (d ? bsb : bsf)[g*H_ + r] : 0.f;
}

// ======================= gx GEMM (R4/R7 verbatim) =======================
template<typename GXT>
__global__ __launch_bounds__(256) void gemm_gx(
    const unsigned short* __restrict__ X, int lda, int K,
    const unsigned short* __restrict__ W,
    const float* __restrict__ bias,
    GXT* __restrict__ gx,
    const int* __restrict__ lens)
{
  const int t = blockIdx.y;
  if (t >= lens[0]) return;
  const int n0 = blockIdx.x * 128;
  __shared__ unsigned short As[128*64];
  __shared__ unsigned short Bs[128*64];
  const int tid = threadIdx.x;
  const int l = tid & 63;
  const int w = tid >> 6;
  const int wm = (w >> 1) * 64, wn = (w & 1) * 64;
  const int lr = l & 15, lk = l >> 4;
  f32x4 acc[4][4];
  #pragma unroll
  for (int i = 0; i < 4; ++i)
    #pragma unroll
    for (int j = 0; j < 4; ++j) acc[i][j] = (f32x4){0.f,0.f,0.f,0.f};

  const unsigned short* Xb = X + (size_t)t * B_ * lda;
  const int r_ = tid >> 3, s_ = (tid & 7) * 8;

  for (int k0 = 0; k0 < K; k0 += 64){
    us8 va[4], vb[4];
    #pragma unroll
    for (int i = 0; i < 4; ++i){
      const int r = i*32 + r_;
      va[i] = *(const us8*)(Xb + (size_t)r*lda + k0 + s_);
      vb[i] = *(const us8*)(W  + (size_t)(n0 + r)*K + k0 + s_);
    }
    __syncthreads();
    #pragma unroll
    for (int i = 0; i < 4; ++i){
      const int r = i*32 + r_;
      *(us8*)&As[r*64 + s_] = va[i];
      *(us8*)&Bs[r*64 + s_] = vb[i];
    }
    __syncthreads();
    #pragma unroll
    for (int kk = 0; kk < 2; ++kk){
      bf16x8 af[4], bfr[4];
      #pragma unroll
      for (int mi = 0; mi < 4; ++mi)
        af[mi] = __builtin_bit_cast(bf16x8, *(const us8*)&As[(wm + mi*16 + lr)*64 + kk*32 + lk*8]);
      #pragma unroll
      for (int ni = 0; ni < 4; ++ni)
        bfr[ni] = __builtin_bit_cast(bf16x8, *(const us8*)&Bs[(wn + ni*16 + lr)*64 + kk*32 + lk*8]);
      #pragma unroll
      for (int mi = 0; mi < 4; ++mi)
        #pragma unroll
        for (int ni = 0; ni < 4; ++ni)
          acc[mi][ni] = __builtin_amdgcn_mfma_f32_16x16x32_bf16(af[mi], bfr[ni], acc[mi][ni], 0, 0, 0);
    }
  }
  #pragma unroll
  for (int ni = 0; ni < 4; ++ni){
    const int col = n0 + wn + ni*16 + lr;
    const float bv = bias[col];
    #pragma unroll
    for (int mi = 0; mi < 4; ++mi){
      #pragma unroll
      for (int r = 0; r < 4; ++r){
        const int b = wm + mi*16 + lk*4 + r;
        store_gx(gx + ((size_t)t*B_ + b)*NW + col, acc[mi][ni][r] + bv);
      }
    }
  }
}

// ======================= recurrent (R7 + pipelined exchange) =============
// grid: 208 blocks = dir(2) x group(8 of 16 batches) x htile(13 of 32 cols)
// wave w (of 4) owns gate w; 26 Whh B-fragments in 104 VGPRs (R7).
// DELTA vs R7: staging first-pass loads + gx loads for step s+1 are issued
// between GC-write(s) and the second barrier -> MALL latency overlaps
// cell+publish instead of sitting on the critical path. GXS double-buffered
// (its s+1 write would race cell(s) reads); HS/GC stay single-buffered
// (barrier-separated). Active steps are a contiguous range -> closed-form
// loop, no skip holes in the pipeline. NORMAL launch (no coop).
template<typename GXT, bool LAST>
__global__ __launch_bounds__(256, 1) void lstm_rec(
    const GXT* __restrict__ gx,
    const unsigned short* __restrict__ whhR,   // [2][13][4][2][13][64][8] bf16
    const int* __restrict__ lens,
    unsigned long long* hbt,                   // tagged h (host-zeroed)
    unsigned short* __restrict__ xn,           // [T][128][832] bf16 (or unused)
    float* __restrict__ out)                   // [T][128][800] f32 (or unused)
{
  __shared__ unsigned short HS[16*424];        // 13568 B
  __shared__ float GC[4*GC_FSTRIDE];           // 9216 B
  __shared__ float GXS[2*16*132];              // 16896 B (double-buffered)

  const int tid = threadIdx.x;
  const int bid = blockIdx.x;
  const int dir  = bid / 104;
  const int rem  = bid % 104;
  const int grp  = rem / NTILES;
  const int tile = rem % NTILES;
  const int l  = tid & 63;
  const int w  = tid >> 6;
  const int lr = l & 15;
  const int lk = l >> 4;
  const int cid = dir*NGRP + grp;

  // Whh B-fragments -> 104 VGPRs (loop-invariant)
  us8 Bf0[13], Bf1[13];
  {
    const unsigned short* bs =
        whhR + ((size_t)((dir*13 + tile)*4 + w)*2*13*64 + l)*8;
    #pragma unroll
    for (int kk = 0; kk < 13; ++kk)
      Bf0[kk] = *(const us8*)(bs + (size_t)kk*512);
    const unsigned short* bs1 = bs + (size_t)13*64*8;
    #pragma unroll
    for (int kk = 0; kk < 13; ++kk)
      Bf1[kk] = *(const us8*)(bs1 + (size_t)kk*512);
  }
  const int grp_len = lens[grp*16];          // lens sorted desc -> group max
  const int eb  = tid & 15;                  // elementwise batch
  const int p2  = tid >> 4;                  // col pair within tile
  const int mylen = lens[grp*16 + eb];
  float cs0 = 0.f, cs1 = 0.f, hs0 = 0.f, hs1 = 0.f;
  __syncthreads();

  const int pb = tid >> 4, q = tid & 15, qg = q >> 2, qj = (q & 3) * 8;
  unsigned long long* const myslot =
      hbt + (((size_t)cid*2)*16 + eb)*PAIRS + tile*16 + p2;

  const int nsteps = grp_len;                // active steps: contiguous
  f32x4 pfa, pfb;
  unsigned long long v[13];

  // ---- prologue: issue loads for step 0 ----
  {
    const int t0 = dir ? (grp_len - 1) : 0;
    const size_t goff = ((size_t)t0*B_ + grp*16 + pb) * NW + (size_t)dir*GP + qg*HP + tile*32 + qj;
    if constexpr (sizeof(GXT) == 4){
      const float* gp = (const float*)gx + goff;
      pfa = *(const f32x4*)gp;
      pfb = *(const f32x4*)(gp + 4);
    } else {
      us8 vv = *(const us8*)((const unsigned short*)gx + goff);
      pfa = (f32x4){bf2f(vv[0]), bf2f(vv[1]), bf2f(vv[2]), bf2f(vv[3])};
      pfb = (f32x4){bf2f(vv[4]), bf2f(vv[5]), bf2f(vv[6]), bf2f(vv[7])};
    }
    const unsigned long long* hb0 = hbt + ((size_t)(cid*2 + 0)*16)*PAIRS;
    #pragma unroll
    for (int j = 0; j < 13; ++j)
      v[j] = h_load_u64(hb0 + j*256 + tid);
  }

  for (int ss = 0; ss < nsteps; ++ss){
    const int t = dir ? (grp_len - 1 - ss) : ss;

    // ---- validate pre-issued staging lines; retry stale ----
    {
      const unsigned rtag = (unsigned)ss;
      const unsigned long long* hb = hbt + ((size_t)(cid*2 + (ss & 1))*16)*PAIRS;
      unsigned stale = 0;
      #pragma unroll
      for (int j = 0; j < 13; ++j)
        if ((unsigned)(v[j] >> 32) != rtag) stale |= 1u << j;
      while (stale){
        const unsigned m = stale;
        #pragma unroll
        for (int j = 0; j < 13; ++j)
          if (m & (1u << j)) v[j] = h_load_u64(hb + j*256 + tid);
        #pragma unroll
        for (int j = 0; j < 13; ++j)
          if ((m & (1u << j)) && (unsigned)(v[j] >> 32) == rtag) stale &= ~(1u << j);
      }
      #pragma unroll
      for (int j = 0; j < 13; ++j){
        const int idx = j*256 + tid;
        const int b = idx / PAIRS, p = idx % PAIRS;
        *(unsigned*)&HS[b*424 + 2*p] = (unsigned)v[j];
      }
    }
    // ---- gx -> GXS[parity] ----
    {
      float* gp = GXS + (ss & 1)*2112 + pb*132 + qg*32 + qj;
      *(f32x4*)gp = pfa;
      *(f32x4*)(gp + 4) = pfb;
    }
    __syncthreads();

    // ---- 26 MFMAs: gate w, both col-halves ----
    f32x4 a0 = (f32x4){0.f,0.f,0.f,0.f}, a1 = (f32x4){0.f,0.f,0.f,0.f};
    {
      const int ab = lr*424 + lk*8;
      #pragma unroll
      for (int kk = 0; kk < 13; ++kk){
        bf16x8 av = __builtin_bit_cast(bf16x8, *(const us8*)&HS[ab + kk*32]);
        a0 = __builtin_amdgcn_mfma_f32_16x16x32_bf16(av, Bf0[kk], a0, 0, 0, 0);
        a1 = __builtin_amdgcn_mfma_f32_16x16x32_bf16(av, Bf1[kk], a1, 0, 0, 0);
      }
    }
    // ---- publish gate partials to GC ----
    {
      float* Gw = GC + w * GC_FSTRIDE;
      #pragma unroll
      for (int r = 0; r < 4; ++r){
        Gw[(lk*4 + r)*36 + lr]      = a0[r];
        Gw[(lk*4 + r)*36 + 16 + lr] = a1[r];
      }
    }
    // ---- issue next-step loads (fly during b2 + cell + publish) ----
    if (ss + 1 < nsteps){
      const int tn = dir ? (grp_len - 2 - ss) : (ss + 1);
      const size_t goff = ((size_t)tn*B_ + grp*16 + pb) * NW + (size_t)dir*GP + qg*HP + tile*32 + qj;
      if constexpr (sizeof(GXT) == 4){
        const float* gp = (const float*)gx + goff;
        pfa = *(const f32x4*)gp;
        pfb = *(const f32x4*)(gp + 4);
      } else {
        us8 vv = *(const us8*)((const unsigned short*)gx + goff);
        pfa = (f32x4){bf2f(vv[0]), bf2f(vv[1]), bf2f(vv[2]), bf2f(vv[3])};
        pfb = (f32x4){bf2f(vv[4]), bf2f(vv[5]), bf2f(vv[6]), bf2f(vv[7])};
      }
      const unsigned long long* hbn = hbt + ((size_t)(cid*2 + ((ss + 1) & 1))*16)*PAIRS;
      #pragma unroll
      for (int j = 0; j < 13; ++j)
        v[j] = h_load_u64(hbn + j*256 + tid);
    }
    __syncthreads();

    // ---- elementwise LSTM cell: thread owns (b=eb, cols {2*p2, 2*p2+1}) ----
    const bool act = t < mylen;
    const int c0 = 2*p2, c1 = 2*p2 + 1;
    {
      const float* GXp = GXS + (ss & 1)*2112;
      const float gi0 = GC[0*GC_FSTRIDE + eb*36 + c0] + GXp[eb*132 + c0];
      const float gf0 = GC[1*GC_FSTRIDE + eb*36 + c0] + GXp[eb*132 + 32 + c0];
      const float gg0 = GC[2*GC_FSTRIDE + eb*36 + c0] + GXp[eb*132 + 64 + c0];
      const float go0 = GC[3*GC_FSTRIDE + eb*36 + c0] + GXp[eb*132 + 96 + c0];
      const float gi1 = GC[0*GC_FSTRIDE + eb*36 + c1] + GXp[eb*132 + c1];
      const float gf1 = GC[1*GC_FSTRIDE + eb*36 + c1] + GXp[eb*132 + 32 + c1];
      const float gg1 = GC[2*GC_FSTRIDE + eb*36 + c1] + GXp[eb*132 + 64 + c1];
      const float go1 = GC[3*GC_FSTRIDE + eb*36 + c1] + GXp[eb*132 + 96 + c1];
      const float cn0 = sigm(gf0)*cs0 + sigm(gi0)*tanh_f(gg0);
      const float hn0 = sigm(go0) * tanh_f(cn0);
      const float cn1 = sigm(gf1)*cs1 + sigm(gi1)*tanh_f(gg1);
      const float hn1 = sigm(go1) * tanh_f(cn1);
      if (act){ cs0 = cn0; hs0 = hn0; cs1 = cn1; hs1 = hn1; }
    }
    // ---- publish tagged h (frozen value if masked) into next parity slot ----
    {
      const unsigned hu = (unsigned)f2bf(hs0) | ((unsigned)f2bf(hs1) << 16);
      const unsigned long long hv =
          (unsigned long long)hu | ((unsigned long long)(unsigned)(ss + 1) << 32);
      h_store_u64(myslot + ((size_t)((ss + 1) & 1))*16*PAIRS, hv);
    }
    // ---- layer outputs ----
    if (act){
      const int bg = grp*16 + eb;
      const int hc = tile*32 + c0;
      if constexpr (LAST){
        float* op = out + ((size_t)t*B_ + bg)*800 + dir*H_ + hc;
        if (hc < H_)     op[0] = hs0;
        if (hc + 1 < H_) op[1] = hs1;
      } else {
        const unsigned hu = (unsigned)f2bf(hs0) | ((unsigned)f2bf(hs1) << 16);
        *(unsigned*)(xn + ((size_t)t*B_ + bg)*832 + (size_t)dir*HP + hc) = hu;
      }
    }
  }
}

// ======================= host side =======================
template<typename GXT>
static void run_all(void* const* din, float* out, char* ws, hipStream_t stream)
{
  const float* x      = (const float*)din[0];
  const int* lens     = (const int*)din[1];
  const float* wihf0  = (const float*)din[2];
  const float* wihf12 = (const float*)din[3];
  const float* whhf   = (const float*)din[4];
  const float* bsf    = (const float*)din[5];
  const float* wihb0  = (const float*)din[6];
  const float* wihb12 = (const float*)din[7];
  const float* whhb   = (const float*)din[8];
  const float* bsb    = (const float*)din[9];

  char* p = ws;
  auto alloc = [&](size_t n){ char* r = p; p += (n + 255) & ~(size_t)255; return r; };
  GXT* gx            = (GXT*)alloc((size_t)T_*B_*NW*sizeof(GXT));
  unsigned short* xA = (unsigned short*)alloc((size_t)T_*B_*832*2);
  unsigned short* xB = (unsigned short*)alloc((size_t)T_*B_*832*2);
  unsigned short* wihp = (unsigned short*)alloc((size_t)NW*K12P*2);
  unsigned short* whhR = (unsigned short*)alloc(WHHR_BYTES);
  float* biasp       = (float*)alloc((size_t)NW*4);
  unsigned long long* hbt = (unsigned long long*)alloc(HBT_BYTES);

  hipMemsetAsync(out, 0, (size_t)T_*B_*800*4, stream);
  {
    size_t n = (size_t)T_*B_*K0P;
    k_conv_x0<<<dim3((unsigned)((n+255)/256)), dim3(256), 0, stream>>>(x, xA);
  }

  const unsigned short* xin[3] = {xA, xB, xA};
  unsigned short* xout[3] = {xB, xA, nullptr};
  const int ldas[3] = {K0P, 832, 832};
  const int Ks[3]   = {K0P, K12P, K12P};

  for (int lyr = 0; lyr < 3; ++lyr){
    const float* wf = (lyr == 0) ? wihf0 : wihf12 + (size_t)(lyr-1)*1600*800;
    const float* wb = (lyr == 0) ? wihb0 : wihb12 + (size_t)(lyr-1)*1600*800;
    {
      size_t n = (size_t)NW*Ks[lyr];
      k_prep_wih<<<dim3((unsigned)((n+255)/256)), dim3(256), 0, stream>>>(
          wf, wb, Ks[lyr], lyr ? 1 : 0, wihp);
    }
    k_prep_bias<<<dim3((NW+255)/256), dim3(256), 0, stream>>>(
        bsf + (size_t)lyr*1600, bsb + (size_t)lyr*1600, biasp);
    gemm_gx<GXT><<<dim3(26, 512), dim3(256), 0, stream>>>(
        xin[lyr], ldas[lyr], Ks[lyr], wihp, biasp, gx, lens);
    {
      size_t n = WHHR_US8;
      k_prep_whhR<<<dim3((unsigned)((n+255)/256)), dim3(256), 0, stream>>>(
          whhf + (size_t)lyr*1600*400, whhb + (size_t)lyr*1600*400, whhR);
    }
    hipMemsetAsync(hbt, 0, HBT_BYTES, stream);

    if (lyr < 2)
      lstm_rec<GXT,false><<<dim3(REC_BLOCKS), dim3(256), 0, stream>>>(
          gx, whhR, lens, hbt, xout[lyr], out);
    else
      lstm_rec<GXT,true><<<dim3(REC_BLOCKS), dim3(256), 0, stream>>>(
          gx, whhR, lens, hbt, nullptr, out);
  }
}

extern "C" void kernel_launch(void* const* d_in, const int* in_sizes, int n_in,
                              void* d_out, int out_size, void* d_ws, size_t ws_size,
                              hipStream_t stream)
{
  (void)in_sizes; (void)n_in; (void)out_size;
  auto align = [](size_t n){ return (n + 255) & ~(size_t)255; };
  const size_t fixed =
      align((size_t)T_*B_*832*2) * 2 +
      align((size_t)NW*K12P*2) +
      align(WHHR_BYTES) +
      align((size_t)NW*4) +
      align(HBT_BYTES);
  const size_t need32 = align((size_t)T_*B_*NW*4) + fixed;
  const size_t need16 = align((size_t)T_*B_*NW*2) + fixed;

  if (ws_size >= need32)
    run_all<float>(d_in, (float*)d_out, (char*)d_ws, stream);
  else if (ws_size >= need16)
    run_all<unsigned short>(d_in, (float*)d_out, (char*)d_ws, stream);
  else
    hipMemsetAsync(d_out, 0, (size_t)T_*B_*800*4, stream);
}

// Round 11
// 6327.040 us; speedup vs baseline: 1.3115x; 1.0451x over previous
//
#include <hip/hip_runtime.h>
#include <stdint.h>
#include <stddef.h>

#define T_ 512
#define B_ 128
#define D_ 400
#define H_ 400
#define HP 416
#define GP 1664            // 4*HP (per-dir padded gate dim)
#define NW 3328            // both dirs stacked
#define K0P 448            // padded K for layer 0 GEMM
#define K12P 832           // padded K for layers 1,2 GEMM
#define NTILES 13          // h tiles of 32 per dir
#define NGRP 8             // batch groups of 16
#define REC_BLOCKS 208     // 2*8*13
#define PAIRS 208          // 416 cols / 2 per batch row (u64 slots)

// GC float stride
#define GC_FSTRIDE 576     // 16*36

// tagged h buffer: [16 cid][2 parity][16 batch][208 pair] u64
#define HBT_U64   ((size_t)16*2*16*PAIRS)
#define HBT_BYTES (HBT_U64*8)

// Whh register-fragment blob: [2 dir][13 tile][4 gate][2 chalf][13 kk][64 lane][8]
#define WHHR_US8  ((size_t)2*13*4*2*13*64)
#define WHHR_BYTES (WHHR_US8*8*2)

typedef __attribute__((ext_vector_type(8))) __bf16 bf16x8;
typedef __attribute__((ext_vector_type(4))) float f32x4;
typedef __attribute__((ext_vector_type(8))) unsigned short us8;

__device__ __forceinline__ unsigned short f2bf(float f){
  unsigned u = __builtin_bit_cast(unsigned, f);
  u = (u + 0x7FFFu + ((u >> 16) & 1u)) >> 16;
  return (unsigned short)u;
}
__device__ __forceinline__ float bf2f(unsigned short s){
  unsigned u = ((unsigned)s) << 16;
  return __builtin_bit_cast(float, u);
}
__device__ __forceinline__ float sigm(float x){ return 1.f / (1.f + __expf(-x)); }
__device__ __forceinline__ float tanh_f(float x){
  float ax = fabsf(x);
  float e = __expf(-2.f * ax);
  float t = (1.f - e) / (1.f + e);
  return x < 0.f ? -t : t;
}
__device__ __forceinline__ void store_gx(float* p, float v){ *p = v; }
__device__ __forceinline__ void store_gx(unsigned short* p, float v){ *p = f2bf(v); }

// agent-scope relaxed atomics == MALL-coherent accesses, NO cache maintenance
__device__ __forceinline__ void h_store_u64(unsigned long long* p, unsigned long long v){
  __hip_atomic_store(p, v, __ATOMIC_RELAXED, __HIP_MEMORY_SCOPE_AGENT);
}
__device__ __forceinline__ unsigned long long h_load_u64(const unsigned long long* p){
  return __hip_atomic_load(p, __ATOMIC_RELAXED, __HIP_MEMORY_SCOPE_AGENT);
}

// async global->LDS, 16B per lane; LDS dest = wave-uniform base + lane*16
__device__ __forceinline__ void gl_lds16(const unsigned short* g, unsigned short* l){
  __builtin_amdgcn_global_load_lds(
      (const __attribute__((address_space(1))) unsigned int*)g,
      (__attribute__((address_space(3))) unsigned int*)l, 16, 0, 0);
}

// ======================= prep kernels =======================
__global__ void k_conv_x0(const float* __restrict__ x, unsigned short* __restrict__ xa){
  const size_t i = (size_t)blockIdx.x*256 + threadIdx.x;
  if (i >= (size_t)T_*B_*K0P) return;
  const int k = (int)(i % K0P);
  const size_t tb = i / K0P;
  xa[i] = f2bf(k < D_ ? x[tb*D_ + k] : 0.f);
}

__global__ void k_prep_wih(const float* __restrict__ wf, const float* __restrict__ wb,
                           int K, int mode, unsigned short* __restrict__ dst){
  const size_t i = (size_t)blockIdx.x*256 + threadIdx.x;
  if (i >= (size_t)NW*K) return;
  const int k = (int)(i % K);
  const int n = (int)(i / K);
  const int d = n / GP, ng = n % GP, g = ng / HP, r = ng % HP;
  const float* Wsrc = d ? wb : wf;
  float v = 0.f;
  if (r < H_){
    if (mode == 0){                       // layer 0: K real 400
      if (k < D_) v = Wsrc[(size_t)(g*H_ + r)*D_ + k];
    } else {                              // layers 1,2: [fwd400|pad16|bwd400|pad16]
      int ks = (k < 400) ? k : ((k >= 416 && k < 816) ? (k - 16) : -1);
      if (ks >= 0) v = Wsrc[(size_t)(g*H_ + r)*800 + ks];
    }
  }
  dst[i] = f2bf(v);
}

// Whh -> per-(dir,tile,gate,chalf) MFMA B-fragments (R7-verified layout):
// lane l holds col c = tile*32 + ch*16 + (l&15), k = kk*32 + (l>>4)*8 + e.
__global__ void k_prep_whhR(const float* __restrict__ wf, const float* __restrict__ wb,
                            unsigned short* __restrict__ dst){
  const size_t i = (size_t)blockIdx.x*256 + threadIdx.x;
  if (i >= WHHR_US8) return;
  const int lane = (int)(i & 63);
  size_t q = i >> 6;
  const int kk = (int)(q % 13); q /= 13;
  const int ch = (int)(q % 2);  q /= 2;
  const int w  = (int)(q % 4);  q /= 4;
  const int tile = (int)(q % 13);
  const int dirx = (int)(q / 13);
  const int c  = tile*32 + ch*16 + (lane & 15);
  const int k0 = kk*32 + (lane >> 4)*8;
  const float* W = dirx ? wb : wf;
  unsigned short v[8];
  #pragma unroll
  for (int e = 0; e < 8; ++e){
    const int k = k0 + e;
    const float x = (c < H_ && k < H_) ? W[(size_t)(w*H_ + c)*H_ + k] : 0.f;
    v[e] = f2bf(x);
  }
  *(us8*)(dst + i*8) = *(const us8*)v;
}

__global__ void k_prep_bias(const float* __restrict__ bsf, const float* __restrict__ bsb,
                            float* __restrict__ dst){
  const int n = blockIdx.x*256 + threadIdx.x;
  if (n >= NW) return;
  const int d = n / GP, ng = n % GP, g = ng / HP, r = ng % HP;
  dst[n] = (r < H_) ? (d ? bsb : bsf)[g*H_ + r] : 0.f;
}

// ======================= gx GEMM (R7 + global_load_lds staging) ==========
// DELTA vs R7: staging uses width-16 global_load_lds (async DMA to LDS, no
// VGPR round-trip, no pre-barrier load drain). Wave w stages rows
// [w*32,w*32+32) of A and B tiles in 4 chunks of 8 rows; lane l sources
// row+(l>>3), kcol (l&7)*8 -> linear LDS dest base+l*16. MFMA/epilogue
// unchanged (proven R4/R7 convention).
template<typename GXT>
__global__ __launch_bounds__(256) void gemm_gx(
    const unsigned short* __restrict__ X, int lda, int K,
    const unsigned short* __restrict__ W,
    const float* __restrict__ bias,
    GXT* __restrict__ gx,
    const int* __restrict__ lens)
{
  const int t = blockIdx.y;
  if (t >= lens[0]) return;
  const int n0 = blockIdx.x * 128;
  __shared__ unsigned short As[128*64];
  __shared__ unsigned short Bs[128*64];
  const int tid = threadIdx.x;
  const int l = tid & 63;
  const int w = tid >> 6;
  const int wm = (w >> 1) * 64, wn = (w & 1) * 64;
  const int lr = l & 15, lk = l >> 4;
  f32x4 acc[4][4];
  #pragma unroll
  for (int i = 0; i < 4; ++i)
    #pragma unroll
    for (int j = 0; j < 4; ++j) acc[i][j] = (f32x4){0.f,0.f,0.f,0.f};

  const unsigned short* Xb = X + (size_t)t * B_ * lda;
  const int srow = l >> 3, scol = (l & 7) * 8;

  for (int k0 = 0; k0 < K; k0 += 64){
    #pragma unroll
    for (int c = 0; c < 4; ++c){
      const int rb = w*32 + c*8;
      gl_lds16(Xb + (size_t)(rb + srow)*lda + k0 + scol, &As[rb*64]);
      gl_lds16(W  + (size_t)(n0 + rb + srow)*K  + k0 + scol, &Bs[rb*64]);
    }
    __syncthreads();
    #pragma unroll
    for (int kk = 0; kk < 2; ++kk){
      bf16x8 af[4], bfr[4];
      #pragma unroll
      for (int mi = 0; mi < 4; ++mi)
        af[mi] = __builtin_bit_cast(bf16x8, *(const us8*)&As[(wm + mi*16 + lr)*64 + kk*32 + lk*8]);
      #pragma unroll
      for (int ni = 0; ni < 4; ++ni)
        bfr[ni] = __builtin_bit_cast(bf16x8, *(const us8*)&Bs[(wn + ni*16 + lr)*64 + kk*32 + lk*8]);
      #pragma unroll
      for (int mi = 0; mi < 4; ++mi)
        #pragma unroll
        for (int ni = 0; ni < 4; ++ni)
          acc[mi][ni] = __builtin_amdgcn_mfma_f32_16x16x32_bf16(af[mi], bfr[ni], acc[mi][ni], 0, 0, 0);
    }
    __syncthreads();
  }
  #pragma unroll
  for (int ni = 0; ni < 4; ++ni){
    const int col = n0 + wn + ni*16 + lr;
    const float bv = bias[col];
    #pragma unroll
    for (int mi = 0; mi < 4; ++mi){
      #pragma unroll
      for (int r = 0; r < 4; ++r){
        const int b = wm + mi*16 + lk*4 + r;
        store_gx(gx + ((size_t)t*B_ + b)*NW + col, acc[mi][ni][r] + bv);
      }
    }
  }
}

// ======================= recurrent (R7 verbatim; normal launch) ==========
// grid: 208 blocks = dir(2) x group(8 of 16 batches) x htile(13 of 32 cols)
// wave w (of 4) owns gate w; its 26 Whh B-fragments live in 104 VGPRs
// (loop-invariant). h exchange: tagged u64 {2x bf16, step tag} via MALL
// relaxed atomics (fire-and-forget producers, tag-retry consumers).
// Normal launch (no coop): protocol needs no grid barrier; 208 blocks
// <= 256 CUs so all are resident immediately (R9-verified).
template<typename GXT, bool LAST>
__global__ __launch_bounds__(256, 1) void lstm_rec(
    const GXT* __restrict__ gx,
    const unsigned short* __restrict__ whhR,   // [2][13][4][2][13][64][8] bf16
    const int* __restrict__ lens,
    unsigned long long* hbt,                   // tagged h (host-zeroed)
    unsigned short* __restrict__ xn,           // [T][128][832] bf16 (or unused)
    float* __restrict__ out)                   // [T][128][800] f32 (or unused)
{
  __shared__ unsigned short HS[16*424];        // 13568 B
  __shared__ float GC[4*GC_FSTRIDE];           // 9216 B
  __shared__ float GXS[16*132];                // 8448 B

  const int tid = threadIdx.x;
  const int bid = blockIdx.x;
  const int dir  = bid / 104;
  const int rem  = bid % 104;
  const int grp  = rem / NTILES;
  const int tile = rem % NTILES;
  const int l  = tid & 63;
  const int w  = tid >> 6;
  const int lr = l & 15;
  const int lk = l >> 4;
  const int cid = dir*NGRP + grp;

  // Whh B-fragments -> 104 VGPRs (loop-invariant)
  us8 Bf0[13], Bf1[13];
  {
    const unsigned short* bs =
        whhR + ((size_t)((dir*13 + tile)*4 + w)*2*13*64 + l)*8;
    #pragma unroll
    for (int kk = 0; kk < 13; ++kk)
      Bf0[kk] = *(const us8*)(bs + (size_t)kk*512);
    const unsigned short* bs1 = bs + (size_t)13*64*8;
    #pragma unroll
    for (int kk = 0; kk < 13; ++kk)
      Bf1[kk] = *(const us8*)(bs1 + (size_t)kk*512);
  }
  const int grp_len = lens[grp*16];          // lens sorted desc -> group max
  const int eb  = tid & 15;                  // elementwise batch
  const int p2  = tid >> 4;                  // col pair within tile
  const int mylen = lens[grp*16 + eb];
  float cs0 = 0.f, cs1 = 0.f, hs0 = 0.f, hs1 = 0.f;
  __syncthreads();

  int s_a = 0;                               // active-step counter (group-uniform)
  const int pb = tid >> 4, q = tid & 15, qg = q >> 2, qj = (q & 3) * 8;
  unsigned long long* const myslot =
      hbt + (((size_t)cid*2)*16 + eb)*PAIRS + tile*16 + p2;

  for (int s = 0; s < T_; ++s){
    const int t = dir ? (T_ - 1 - s) : s;
    if (t >= grp_len) continue;            // whole group idle: uniform skip

    // prefetch gx for this step (in flight during tag-wait)
    f32x4 pfa, pfb;
    {
      const size_t goff = ((size_t)t*B_ + grp*16 + pb) * NW + (size_t)dir*GP + qg*HP + tile*32 + qj;
      if constexpr (sizeof(GXT) == 4){
        const float* gp = (const float*)gx + goff;
        pfa = *(const f32x4*)gp;
        pfb = *(const f32x4*)(gp + 4);
      } else {
        us8 v = *(const us8*)((const unsigned short*)gx + goff);
        pfa = (f32x4){bf2f(v[0]), bf2f(v[1]), bf2f(v[2]), bf2f(v[3])};
        pfb = (f32x4){bf2f(v[4]), bf2f(v[5]), bf2f(v[6]), bf2f(v[7])};
      }
    }

    // ---- stage h (16x416) -> LDS with per-line tag validation ----
    {
      const unsigned rtag = (unsigned)s_a;
      const unsigned long long* hb =
          hbt + ((size_t)(cid*2 + (s_a & 1))*16)*PAIRS;   // [16][208] linear
      unsigned long long v[13];
      #pragma unroll
      for (int j = 0; j < 13; ++j)
        v[j] = h_load_u64(hb + j*256 + tid);
      unsigned stale = 0;
      #pragma unroll
      for (int j = 0; j < 13; ++j)
        if ((unsigned)(v[j] >> 32) != rtag) stale |= 1u << j;
      while (stale){
        const unsigned m = stale;
        #pragma unroll
        for (int j = 0; j < 13; ++j)
          if (m & (1u << j)) v[j] = h_load_u64(hb + j*256 + tid);
        #pragma unroll
        for (int j = 0; j < 13; ++j)
          if ((m & (1u << j)) && (unsigned)(v[j] >> 32) == rtag) stale &= ~(1u << j);
      }
      #pragma unroll
      for (int j = 0; j < 13; ++j){
        const int idx = j*256 + tid;
        const int b = idx / PAIRS, p = idx % PAIRS;
        *(unsigned*)&HS[b*424 + 2*p] = (unsigned)v[j];
      }
    }
    __syncthreads();

    // gates[16 x 32] for gate w: h(16x416) @ Whh_tile^T, B from registers
    f32x4 a0 = (f32x4){0.f,0.f,0.f,0.f}, a1 = (f32x4){0.f,0.f,0.f,0.f};
    {
      const int ab = lr*424 + lk*8;
      #pragma unroll
      for (int kk = 0; kk < 13; ++kk){
        bf16x8 av = __builtin_bit_cast(bf16x8, *(const us8*)&HS[ab + kk*32]);
        a0 = __builtin_amdgcn_mfma_f32_16x16x32_bf16(av, Bf0[kk], a0, 0, 0, 0);
        a1 = __builtin_amdgcn_mfma_f32_16x16x32_bf16(av, Bf1[kk], a1, 0, 0, 0);
      }
    }
    // publish gate partials + gx to LDS
    {
      float* Gw = GC + w * GC_FSTRIDE;
      #pragma unroll
      for (int r = 0; r < 4; ++r){
        Gw[(lk*4 + r)*36 + lr]      = a0[r];
        Gw[(lk*4 + r)*36 + 16 + lr] = a1[r];
      }
      float* gp = GXS + pb*132 + qg*32 + qj;
      *(f32x4*)gp = pfa;
      *(f32x4*)(gp + 4) = pfb;
    }
    __syncthreads();

    // elementwise LSTM cell: thread owns (b=eb, cols {2*p2, 2*p2+1})
    const bool act = t < mylen;
    const int c0 = 2*p2, c1 = 2*p2 + 1;
    {
      const float gi0 = GC[0*GC_FSTRIDE + eb*36 + c0] + GXS[eb*132 + c0];
      const float gf0 = GC[1*GC_FSTRIDE + eb*36 + c0] + GXS[eb*132 + 32 + c0];
      const float gg0 = GC[2*GC_FSTRIDE + eb*36 + c0] + GXS[eb*132 + 64 + c0];
      const float go0 = GC[3*GC_FSTRIDE + eb*36 + c0] + GXS[eb*132 + 96 + c0];
      const float gi1 = GC[0*GC_FSTRIDE + eb*36 + c1] + GXS[eb*132 + c1];
      const float gf1 = GC[1*GC_FSTRIDE + eb*36 + c1] + GXS[eb*132 + 32 + c1];
      const float gg1 = GC[2*GC_FSTRIDE + eb*36 + c1] + GXS[eb*132 + 64 + c1];
      const float go1 = GC[3*GC_FSTRIDE + eb*36 + c1] + GXS[eb*132 + 96 + c1];
      const float cn0 = sigm(gf0)*cs0 + sigm(gi0)*tanh_f(gg0);
      const float hn0 = sigm(go0) * tanh_f(cn0);
      const float cn1 = sigm(gf1)*cs1 + sigm(gi1)*tanh_f(gg1);
      const float hn1 = sigm(go1) * tanh_f(cn1);
      if (act){ cs0 = cn0; hs0 = hn0; cs1 = cn1; hs1 = hn1; }
    }
    // publish tagged h (frozen value if masked) into next parity slot
    {
      const unsigned hu = (unsigned)f2bf(hs0) | ((unsigned)f2bf(hs1) << 16);
      const unsigned long long hv =
          (unsigned long long)hu | ((unsigned long long)(unsigned)(s_a + 1) << 32);
      h_store_u64(myslot + ((size_t)((s_a + 1) & 1))*16*PAIRS, hv);
    }
    if (act){
      const int bg = grp*16 + eb;
      const int hc = tile*32 + c0;
      if constexpr (LAST){
        float* op = out + ((size_t)t*B_ + bg)*800 + dir*H_ + hc;
        if (hc < H_)     op[0] = hs0;
        if (hc + 1 < H_) op[1] = hs1;
      } else {
        const unsigned hu = (unsigned)f2bf(hs0) | ((unsigned)f2bf(hs1) << 16);
        *(unsigned*)(xn + ((size_t)t*B_ + bg)*832 + (size_t)dir*HP + hc) = hu;
      }
    }
    ++s_a;
  }
}

// ======================= host side =======================
template<typename GXT>
static void run_all(void* const* din, float* out, char* ws, hipStream_t stream)
{
  const float* x      = (const float*)din[0];
  const int* lens     = (const int*)din[1];
  const float* wihf0  = (const float*)din[2];
  const float* wihf12 = (const float*)din[3];
  const float* whhf   = (const float*)din[4];
  const float* bsf    = (const float*)din[5];
  const float* wihb0  = (const float*)din[6];
  const float* wihb12 = (const float*)din[7];
  const float* whhb   = (const float*)din[8];
  const float* bsb    = (const float*)din[9];

  char* p = ws;
  auto alloc = [&](size_t n){ char* r = p; p += (n + 255) & ~(size_t)255; return r; };
  GXT* gx            = (GXT*)alloc((size_t)T_*B_*NW*sizeof(GXT));
  unsigned short* xA = (unsigned short*)alloc((size_t)T_*B_*832*2);
  unsigned short* xB = (unsigned short*)alloc((size_t)T_*B_*832*2);
  unsigned short* wihp = (unsigned short*)alloc((size_t)NW*K12P*2);
  unsigned short* whhR = (unsigned short*)alloc(WHHR_BYTES);
  float* biasp       = (float*)alloc((size_t)NW*4);
  unsigned long long* hbt = (unsigned long long*)alloc(HBT_BYTES);

  hipMemsetAsync(out, 0, (size_t)T_*B_*800*4, stream);
  {
    size_t n = (size_t)T_*B_*K0P;
    k_conv_x0<<<dim3((unsigned)((n+255)/256)), dim3(256), 0, stream>>>(x, xA);
  }

  const unsigned short* xin[3] = {xA, xB, xA};
  unsigned short* xout[3] = {xB, xA, nullptr};
  const int ldas[3] = {K0P, 832, 832};
  const int Ks[3]   = {K0P, K12P, K12P};

  for (int lyr = 0; lyr < 3; ++lyr){
    const float* wf = (lyr == 0) ? wihf0 : wihf12 + (size_t)(lyr-1)*1600*800;
    const float* wb = (lyr == 0) ? wihb0 : wihb12 + (size_t)(lyr-1)*1600*800;
    {
      size_t n = (size_t)NW*Ks[lyr];
      k_prep_wih<<<dim3((unsigned)((n+255)/256)), dim3(256), 0, stream>>>(
          wf, wb, Ks[lyr], lyr ? 1 : 0, wihp);
    }
    k_prep_bias<<<dim3((NW+255)/256), dim3(256), 0, stream>>>(
        bsf + (size_t)lyr*1600, bsb + (size_t)lyr*1600, biasp);
    gemm_gx<GXT><<<dim3(26, 512), dim3(256), 0, stream>>>(
        xin[lyr], ldas[lyr], Ks[lyr], wihp, biasp, gx, lens);
    {
      size_t n = WHHR_US8;
      k_prep_whhR<<<dim3((unsigned)((n+255)/256)), dim3(256), 0, stream>>>(
          whhf + (size_t)lyr*1600*400, whhb + (size_t)lyr*1600*400, whhR);
    }
    hipMemsetAsync(hbt, 0, HBT_BYTES, stream);

    if (lyr < 2)
      lstm_rec<GXT,false><<<dim3(REC_BLOCKS), dim3(256), 0, stream>>>(
          gx, whhR, lens, hbt, xout[lyr], out);
    else
      lstm_rec<GXT,true><<<dim3(REC_BLOCKS), dim3(256), 0, stream>>>(
          gx, whhR, lens, hbt, nullptr, out);
  }
}

extern "C" void kernel_launch(void* const* d_in, const int* in_sizes, int n_in,
                              void* d_out, int out_size, void* d_ws, size_t ws_size,
                              hipStream_t stream)
{
  (void)in_sizes; (void)n_in; (void)out_size;
  auto align = [](size_t n){ return (n + 255) & ~(size_t)255; };
  const size_t fixed =
      align((size_t)T_*B_*832*2) * 2 +
      align((size_t)NW*K12P*2) +
      align(WHHR_BYTES) +
      align((size_t)NW*4) +
      align(HBT_BYTES);
  const size_t need32 = align((size_t)T_*B_*NW*4) + fixed;
  const size_t need16 = align((size_t)T_*B_*NW*2) + fixed;

  if (ws_size >= need32)
    run_all<float>(d_in, (float*)d_out, (char*)d_ws, stream);
  else if (ws_size >= need16)
    run_all<unsigned short>(d_in, (float*)d_out, (char*)d_ws, stream);
  else
    hipMemsetAsync(d_out, 0, (size_t)T_*B_*800*4, stream);
}

// Round 12
// 5592.651 us; speedup vs baseline: 1.4837x; 1.1313x over previous
//
#include <hip/hip_runtime.h>
#include <stdint.h>
#include <stddef.h>

#define T_ 512
#define B_ 128
#define D_ 400
#define H_ 400
#define HP 416
#define GP 1664            // 4*HP (per-dir padded gate dim)
#define NW 3328            // both dirs stacked
#define KXP 832            // uniform padded x-K for all layers
#define NTILES 13          // h tiles of 32 per dir
#define NGRP 8             // batch groups of 16
#define REC_BLOCKS 208     // 2*8*13
#define PAIRS 208          // 416 cols / 2 per batch row (u64 slots)

// GC float stride
#define GC_FSTRIDE 576     // 16*36

// tagged h buffer: [16 cid][2 parity][16 batch][208 pair] u64
#define HBT_U64   ((size_t)16*2*16*PAIRS)
#define HBT_BYTES (HBT_U64*8)

// Whh register-fragment blob: [2 dir][13 tile][4 gate][2 ch][13 kk][64 lane][8]
#define WHHR_US8  ((size_t)2*13*4*2*13*64)
#define WHHR_BYTES (WHHR_US8*8*2)
// Wih register-fragment blob: [2 dir][13 tile][4 gate][2 ch][26 kk][64 lane][8]
#define WIHR_US8  ((size_t)2*13*4*2*26*64)
#define WIHR_BYTES (WIHR_US8*8*2)

typedef __attribute__((ext_vector_type(8))) __bf16 bf16x8;
typedef __attribute__((ext_vector_type(4))) float f32x4;
typedef __attribute__((ext_vector_type(8))) unsigned short us8;

__device__ __forceinline__ unsigned short f2bf(float f){
  unsigned u = __builtin_bit_cast(unsigned, f);
  u = (u + 0x7FFFu + ((u >> 16) & 1u)) >> 16;
  return (unsigned short)u;
}
__device__ __forceinline__ float bf2f(unsigned short s){
  unsigned u = ((unsigned)s) << 16;
  return __builtin_bit_cast(float, u);
}
__device__ __forceinline__ float sigm(float x){ return 1.f / (1.f + __expf(-x)); }
__device__ __forceinline__ float tanh_f(float x){
  float ax = fabsf(x);
  float e = __expf(-2.f * ax);
  float t = (1.f - e) / (1.f + e);
  return x < 0.f ? -t : t;
}

// agent-scope relaxed atomics == MALL-coherent accesses, NO cache maintenance
__device__ __forceinline__ void h_store_u64(unsigned long long* p, unsigned long long v){
  __hip_atomic_store(p, v, __ATOMIC_RELAXED, __HIP_MEMORY_SCOPE_AGENT);
}
__device__ __forceinline__ unsigned long long h_load_u64(const unsigned long long* p){
  return __hip_atomic_load(p, __ATOMIC_RELAXED, __HIP_MEMORY_SCOPE_AGENT);
}

// ======================= prep kernels =======================
// layer-0 input -> [T][128][832] bf16 (real 400, zero pad)
__global__ void k_conv_x0(const float* __restrict__ x, unsigned short* __restrict__ xa){
  const size_t i = (size_t)blockIdx.x*256 + threadIdx.x;
  if (i >= (size_t)T_*B_*KXP) return;
  const int k = (int)(i % KXP);
  const size_t tb = i / KXP;
  xa[i] = f2bf(k < D_ ? x[tb*D_ + k] : 0.f);
}

// Wih -> MFMA B-fragments [2 dir][13 tile][4 gate][2 ch][26 kk][64 lane][8]
// lane l: col c = tile*32 + ch*16 + (l&15), k = kk*32 + (l>>4)*8 + e (padded 832)
// mode 0 (layer 0): src K=400, ks = k<400 ? k : -1
// mode 1 (layers 1,2): src K=800, ks = k<400?k : (416<=k<816 ? k-16 : -1)
__global__ void k_prep_wihR(const float* __restrict__ wf, const float* __restrict__ wb,
                            int mode, unsigned short* __restrict__ dst){
  const size_t i = (size_t)blockIdx.x*256 + threadIdx.x;
  if (i >= WIHR_US8) return;
  const int lane = (int)(i & 63);
  size_t q = i >> 6;
  const int kk = (int)(q % 26); q /= 26;
  const int ch = (int)(q % 2);  q /= 2;
  const int g  = (int)(q % 4);  q /= 4;
  const int tile = (int)(q % 13);
  const int dirx = (int)(q / 13);
  const int c  = tile*32 + ch*16 + (lane & 15);
  const int k0 = kk*32 + (lane >> 4)*8;
  const float* W = dirx ? wb : wf;
  const int stride = mode ? 800 : D_;
  unsigned short v[8];
  #pragma unroll
  for (int e = 0; e < 8; ++e){
    const int k = k0 + e;
    int ks;
    if (mode == 0) ks = (k < D_) ? k : -1;
    else           ks = (k < 400) ? k : ((k >= 416 && k < 816) ? (k - 16) : -1);
    const float x = (c < H_ && ks >= 0) ? W[(size_t)(g*H_ + c)*stride + ks] : 0.f;
    v[e] = f2bf(x);
  }
  *(us8*)(dst + i*8) = *(const us8*)v;
}

// Whh -> B-fragments (R7-verified layout)
__global__ void k_prep_whhR(const float* __restrict__ wf, const float* __restrict__ wb,
                            unsigned short* __restrict__ dst){
  const size_t i = (size_t)blockIdx.x*256 + threadIdx.x;
  if (i >= WHHR_US8) return;
  const int lane = (int)(i & 63);
  size_t q = i >> 6;
  const int kk = (int)(q % 13); q /= 13;
  const int ch = (int)(q % 2);  q /= 2;
  const int w  = (int)(q % 4);  q /= 4;
  const int tile = (int)(q % 13);
  const int dirx = (int)(q / 13);
  const int c  = tile*32 + ch*16 + (lane & 15);
  const int k0 = kk*32 + (lane >> 4)*8;
  const float* W = dirx ? wb : wf;
  unsigned short v[8];
  #pragma unroll
  for (int e = 0; e < 8; ++e){
    const int k = k0 + e;
    const float x = (c < H_ && k < H_) ? W[(size_t)(w*H_ + c)*H_ + k] : 0.f;
    v[e] = f2bf(x);
  }
  *(us8*)(dst + i*8) = *(const us8*)v;
}

__global__ void k_prep_bias(const float* __restrict__ bsf, const float* __restrict__ bsb,
                            float* __restrict__ dst){
  const int n = blockIdx.x*256 + threadIdx.x;
  if (n >= NW) return;
  const int d = n / GP, ng = n % GP, g = ng / HP, r = ng % HP;
  dst[n] = (r < H_) ? (d ? bsb : bsf)[g*H_ + r] : 0.f;
}

// ======================= recurrent (fused Wih@x + Whh@h) =================
// grid: 208 blocks = dir(2) x group(8 of 16 batches) x htile(13 of 32 cols)
// wave w owns gate w: 26 Whh B-frags (104 regs) + 52 Wih B-frags (208 regs),
// all loop-invariant. Per step: stage x(t) (plain loads, no tags) + h (tagged
// MALL protocol, R7-verified) -> LDS; 78 MFMAs (52 x-side + 26 h-side);
// GC gate exchange; in-register cell with bias regs; tagged publish.
// gx/GEMM eliminated entirely. Normal launch (R9-verified).
template<bool LAST>
__global__ __launch_bounds__(256, 1) void lstm_rec(
    const unsigned short* __restrict__ xin,    // [T][128][832] bf16
    const unsigned short* __restrict__ wihR,   // Wih fragments
    const unsigned short* __restrict__ whhR,   // Whh fragments
    const float* __restrict__ biasp,           // [NW] f32
    const int* __restrict__ lens,
    unsigned long long* hbt,                   // tagged h (host-zeroed)
    unsigned short* __restrict__ xn,           // [T][128][832] bf16 (or unused)
    float* __restrict__ out)                   // [T][128][800] f32 (or unused)
{
  __shared__ unsigned short HS[16*424];        // 13568 B (h, stride 424)
  __shared__ unsigned short XS[16*840];        // 26880 B (x, stride 840)
  __shared__ float GC[4*GC_FSTRIDE];           // 9216 B

  const int tid = threadIdx.x;
  const int bid = blockIdx.x;
  const int dir  = bid / 104;
  const int rem  = bid % 104;
  const int grp  = rem / NTILES;
  const int tile = rem % NTILES;
  const int l  = tid & 63;
  const int w  = tid >> 6;
  const int lr = l & 15;
  const int lk = l >> 4;
  const int cid = dir*NGRP + grp;

  // Whh B-fragments -> 104 regs (loop-invariant)
  us8 Bf0[13], Bf1[13];
  {
    const unsigned short* bs =
        whhR + ((size_t)((dir*13 + tile)*4 + w)*2*13*64 + l)*8;
    #pragma unroll
    for (int kk = 0; kk < 13; ++kk)
      Bf0[kk] = *(const us8*)(bs + (size_t)kk*512);
    const unsigned short* bs1 = bs + (size_t)13*64*8;
    #pragma unroll
    for (int kk = 0; kk < 13; ++kk)
      Bf1[kk] = *(const us8*)(bs1 + (size_t)kk*512);
  }
  // Wih B-fragments -> 208 regs (loop-invariant)
  us8 Wf0[26], Wf1[26];
  {
    const unsigned short* ws0 =
        wihR + ((size_t)(((dir*13 + tile)*4 + w)*2 + 0)*26*64 + l)*8;
    #pragma unroll
    for (int kk = 0; kk < 26; ++kk)
      Wf0[kk] = *(const us8*)(ws0 + (size_t)kk*512);
    const unsigned short* ws1 = ws0 + (size_t)26*64*8;
    #pragma unroll
    for (int kk = 0; kk < 26; ++kk)
      Wf1[kk] = *(const us8*)(ws1 + (size_t)kk*512);
  }

  const int grp_len = lens[grp*16];          // lens sorted desc -> group max
  const int eb  = tid & 15;                  // elementwise batch
  const int p2  = tid >> 4;                  // col pair within tile
  const int mylen = lens[grp*16 + eb];
  const int c0 = 2*p2, c1 = 2*p2 + 1;
  // bias registers for this thread's (gate, col) set
  float b0g[4], b1g[4];
  #pragma unroll
  for (int g = 0; g < 4; ++g){
    b0g[g] = biasp[dir*GP + g*HP + tile*32 + c0];
    b1g[g] = biasp[dir*GP + g*HP + tile*32 + c1];
  }
  float cs0 = 0.f, cs1 = 0.f, hs0 = 0.f, hs1 = 0.f;
  __syncthreads();

  int s_a = 0;                               // active-step counter (group-uniform)
  unsigned long long* const myslot =
      hbt + (((size_t)cid*2)*16 + eb)*PAIRS + tile*16 + p2;

  for (int s = 0; s < T_; ++s){
    const int t = dir ? (T_ - 1 - s) : s;
    if (t >= grp_len) continue;            // whole group idle: uniform skip

    // ---- issue x(t) row loads (plain, no tags; 13 u64/thread) ----
    unsigned long long vx[13];
    {
      const unsigned long long* xrow =
          (const unsigned long long*)(xin + ((size_t)t*B_ + grp*16)*KXP);
      #pragma unroll
      for (int j = 0; j < 13; ++j){
        const int idx = j*256 + tid;         // [16 b][208 qw]
        const int b = idx / 208, qq = idx % 208;
        vx[j] = xrow[(size_t)b*208 + qq];
      }
    }
    // ---- stage h (16x416) with per-line tag validation ----
    {
      const unsigned rtag = (unsigned)s_a;
      const unsigned long long* hb =
          hbt + ((size_t)(cid*2 + (s_a & 1))*16)*PAIRS;   // [16][208] linear
      unsigned long long v[13];
      #pragma unroll
      for (int j = 0; j < 13; ++j)
        v[j] = h_load_u64(hb + j*256 + tid);
      unsigned stale = 0;
      #pragma unroll
      for (int j = 0; j < 13; ++j)
        if ((unsigned)(v[j] >> 32) != rtag) stale |= 1u << j;
      while (stale){
        const unsigned m = stale;
        #pragma unroll
        for (int j = 0; j < 13; ++j)
          if (m & (1u << j)) v[j] = h_load_u64(hb + j*256 + tid);
        #pragma unroll
        for (int j = 0; j < 13; ++j)
          if ((m & (1u << j)) && (unsigned)(v[j] >> 32) == rtag) stale &= ~(1u << j);
      }
      #pragma unroll
      for (int j = 0; j < 13; ++j){
        const int idx = j*256 + tid;
        const int b = idx / PAIRS, p = idx % PAIRS;
        *(unsigned*)&HS[b*424 + 2*p] = (unsigned)v[j];
      }
    }
    // ---- write x row -> XS (stride 840) ----
    #pragma unroll
    for (int j = 0; j < 13; ++j){
      const int idx = j*256 + tid;
      const int b = idx / 208, qq = idx % 208;
      *(unsigned long long*)&XS[b*840 + qq*4] = vx[j];
    }
    __syncthreads();

    // ---- 78 MFMAs: gate w = Wih@x (52) + Whh@h (26), both col-halves ----
    f32x4 a0 = (f32x4){0.f,0.f,0.f,0.f}, a1 = (f32x4){0.f,0.f,0.f,0.f};
    {
      const int abx = lr*840 + lk*8;
      #pragma unroll
      for (int kk = 0; kk < 26; ++kk){
        bf16x8 xa = __builtin_bit_cast(bf16x8, *(const us8*)&XS[abx + kk*32]);
        a0 = __builtin_amdgcn_mfma_f32_16x16x32_bf16(xa, Wf0[kk], a0, 0, 0, 0);
        a1 = __builtin_amdgcn_mfma_f32_16x16x32_bf16(xa, Wf1[kk], a1, 0, 0, 0);
      }
      const int ab = lr*424 + lk*8;
      #pragma unroll
      for (int kk = 0; kk < 13; ++kk){
        bf16x8 av = __builtin_bit_cast(bf16x8, *(const us8*)&HS[ab + kk*32]);
        a0 = __builtin_amdgcn_mfma_f32_16x16x32_bf16(av, Bf0[kk], a0, 0, 0, 0);
        a1 = __builtin_amdgcn_mfma_f32_16x16x32_bf16(av, Bf1[kk], a1, 0, 0, 0);
      }
    }
    // ---- publish gate partials to GC ----
    {
      float* Gw = GC + w * GC_FSTRIDE;
      #pragma unroll
      for (int r = 0; r < 4; ++r){
        Gw[(lk*4 + r)*36 + lr]      = a0[r];
        Gw[(lk*4 + r)*36 + 16 + lr] = a1[r];
      }
    }
    __syncthreads();

    // ---- elementwise LSTM cell: thread owns (b=eb, cols {c0, c1}) ----
    const bool act = t < mylen;
    {
      const float gi0 = GC[0*GC_FSTRIDE + eb*36 + c0] + b0g[0];
      const float gf0 = GC[1*GC_FSTRIDE + eb*36 + c0] + b0g[1];
      const float gg0 = GC[2*GC_FSTRIDE + eb*36 + c0] + b0g[2];
      const float go0 = GC[3*GC_FSTRIDE + eb*36 + c0] + b0g[3];
      const float gi1 = GC[0*GC_FSTRIDE + eb*36 + c1] + b1g[0];
      const float gf1 = GC[1*GC_FSTRIDE + eb*36 + c1] + b1g[1];
      const float gg1 = GC[2*GC_FSTRIDE + eb*36 + c1] + b1g[2];
      const float go1 = GC[3*GC_FSTRIDE + eb*36 + c1] + b1g[3];
      const float cn0 = sigm(gf0)*cs0 + sigm(gi0)*tanh_f(gg0);
      const float hn0 = sigm(go0) * tanh_f(cn0);
      const float cn1 = sigm(gf1)*cs1 + sigm(gi1)*tanh_f(gg1);
      const float hn1 = sigm(go1) * tanh_f(cn1);
      if (act){ cs0 = cn0; hs0 = hn0; cs1 = cn1; hs1 = hn1; }
    }
    // ---- publish tagged h (frozen value if masked) into next parity slot ----
    {
      const unsigned hu = (unsigned)f2bf(hs0) | ((unsigned)f2bf(hs1) << 16);
      const unsigned long long hv =
          (unsigned long long)hu | ((unsigned long long)(unsigned)(s_a + 1) << 32);
      h_store_u64(myslot + ((size_t)((s_a + 1) & 1))*16*PAIRS, hv);
    }
    // ---- layer outputs ----
    if (act){
      const int bg = grp*16 + eb;
      const int hc = tile*32 + c0;
      if constexpr (LAST){
        float* op = out + ((size_t)t*B_ + bg)*800 + dir*H_ + hc;
        if (hc < H_)     op[0] = hs0;
        if (hc + 1 < H_) op[1] = hs1;
      } else {
        const unsigned hu = (unsigned)f2bf(hs0) | ((unsigned)f2bf(hs1) << 16);
        *(unsigned*)(xn + ((size_t)t*B_ + bg)*KXP + (size_t)dir*HP + hc) = hu;
      }
    }
    ++s_a;
  }
}

// ======================= host side =======================
static void run_all(void* const* din, float* out, char* ws, hipStream_t stream)
{
  const float* x      = (const float*)din[0];
  const int* lens     = (const int*)din[1];
  const float* wihf0  = (const float*)din[2];
  const float* wihf12 = (const float*)din[3];
  const float* whhf   = (const float*)din[4];
  const float* bsf    = (const float*)din[5];
  const float* wihb0  = (const float*)din[6];
  const float* wihb12 = (const float*)din[7];
  const float* whhb   = (const float*)din[8];
  const float* bsb    = (const float*)din[9];

  char* p = ws;
  auto alloc = [&](size_t n){ char* r = p; p += (n + 255) & ~(size_t)255; return r; };
  unsigned short* xA = (unsigned short*)alloc((size_t)T_*B_*KXP*2);
  unsigned short* xB = (unsigned short*)alloc((size_t)T_*B_*KXP*2);
  unsigned short* wihR = (unsigned short*)alloc(WIHR_BYTES);
  unsigned short* whhR = (unsigned short*)alloc(WHHR_BYTES);
  float* biasp       = (float*)alloc((size_t)NW*4);
  unsigned long long* hbt = (unsigned long long*)alloc(HBT_BYTES);

  hipMemsetAsync(out, 0, (size_t)T_*B_*800*4, stream);
  {
    size_t n = (size_t)T_*B_*KXP;
    k_conv_x0<<<dim3((unsigned)((n+255)/256)), dim3(256), 0, stream>>>(x, xA);
  }

  const unsigned short* xinv[3] = {xA, xB, xA};
  unsigned short* xoutv[3] = {xB, xA, nullptr};

  for (int lyr = 0; lyr < 3; ++lyr){
    const float* wf = (lyr == 0) ? wihf0 : wihf12 + (size_t)(lyr-1)*1600*800;
    const float* wb = (lyr == 0) ? wihb0 : wihb12 + (size_t)(lyr-1)*1600*800;
    {
      size_t n = WIHR_US8;
      k_prep_wihR<<<dim3((unsigned)((n+255)/256)), dim3(256), 0, stream>>>(
          wf, wb, lyr ? 1 : 0, wihR);
    }
    k_prep_bias<<<dim3((NW+255)/256), dim3(256), 0, stream>>>(
        bsf + (size_t)lyr*1600, bsb + (size_t)lyr*1600, biasp);
    {
      size_t n = WHHR_US8;
      k_prep_whhR<<<dim3((unsigned)((n+255)/256)), dim3(256), 0, stream>>>(
          whhf + (size_t)lyr*1600*400, whhb + (size_t)lyr*1600*400, whhR);
    }
    hipMemsetAsync(hbt, 0, HBT_BYTES, stream);

    if (lyr < 2)
      lstm_rec<false><<<dim3(REC_BLOCKS), dim3(256), 0, stream>>>(
          xinv[lyr], wihR, whhR, biasp, lens, hbt, xoutv[lyr], out);
    else
      lstm_rec<true><<<dim3(REC_BLOCKS), dim3(256), 0, stream>>>(
          xinv[lyr], wihR, whhR, biasp, lens, hbt, nullptr, out);
  }
}

extern "C" void kernel_launch(void* const* d_in, const int* in_sizes, int n_in,
                              void* d_out, int out_size, void* d_ws, size_t ws_size,
                              hipStream_t stream)
{
  (void)in_sizes; (void)n_in; (void)out_size;
  auto align = [](size_t n){ return (n + 255) & ~(size_t)255; };
  const size_t need =
      align((size_t)T_*B_*KXP*2) * 2 +
      align(WIHR_BYTES) +
      align(WHHR_BYTES) +
      align((size_t)NW*4) +
      align(HBT_BYTES);

  if (ws_size >= need)
    run_all(d_in, (float*)d_out, (char*)d_ws, stream);
  else
    hipMemsetAsync(d_out, 0, (size_t)T_*B_*800*4, stream);
}

// Round 13
// 5119.929 us; speedup vs baseline: 1.6207x; 1.0923x over previous
//
#include <hip/hip_runtime.h>
#include <stdint.h>
#include <stddef.h>

#define T_ 512
#define B_ 128
#define D_ 400
#define H_ 400
#define HP 416
#define GP 1664            // 4*HP (per-dir padded gate dim)
#define NW 3328            // both dirs stacked
#define KXP 832            // uniform padded x-K for all layers
#define NTILES 13          // h tiles of 32 per dir
#define NGRP 8             // batch groups of 16
#define REC_BLOCKS 208     // 2*8*13
#define PAIRS 208          // 416 cols / 2 per batch row (u64 slots)

// GC float stride
#define GC_FSTRIDE 576     // 16*36

// rec LDS layout (dynamic): HS | XS[2] | GC
#define HS_BYTES  (16*424*2)                 // 13568
#define XS_STRIDE 840
#define XS_BYTES  (16*XS_STRIDE*2)           // 26880
#define XS0_OFF   HS_BYTES
#define XS1_OFF   (HS_BYTES + XS_BYTES)
#define GC_OFF    (HS_BYTES + 2*XS_BYTES)    // 67328
#define LDS_TOTAL (GC_OFF + 4*GC_FSTRIDE*4)  // 76544

// tagged h buffer: [16 cid][2 parity][16 batch][208 pair] u64
#define HBT_U64   ((size_t)16*2*16*PAIRS)
#define HBT_BYTES (HBT_U64*8)

// Whh register-fragment blob: [2 dir][13 tile][4 gate][2 ch][13 kk][64 lane][8]
#define WHHR_US8  ((size_t)2*13*4*2*13*64)
#define WHHR_BYTES (WHHR_US8*8*2)
// Wih register-fragment blob: [2 dir][13 tile][4 gate][2 ch][26 kk][64 lane][8]
#define WIHR_US8  ((size_t)2*13*4*2*26*64)
#define WIHR_BYTES (WIHR_US8*8*2)

typedef __attribute__((ext_vector_type(8))) __bf16 bf16x8;
typedef __attribute__((ext_vector_type(4))) float f32x4;
typedef __attribute__((ext_vector_type(8))) unsigned short us8;

__device__ __forceinline__ unsigned short f2bf(float f){
  unsigned u = __builtin_bit_cast(unsigned, f);
  u = (u + 0x7FFFu + ((u >> 16) & 1u)) >> 16;
  return (unsigned short)u;
}
__device__ __forceinline__ float bf2f(unsigned short s){
  unsigned u = ((unsigned)s) << 16;
  return __builtin_bit_cast(float, u);
}
__device__ __forceinline__ float sigm(float x){ return 1.f / (1.f + __expf(-x)); }
__device__ __forceinline__ float tanh_f(float x){
  float ax = fabsf(x);
  float e = __expf(-2.f * ax);
  float t = (1.f - e) / (1.f + e);
  return x < 0.f ? -t : t;
}

// agent-scope relaxed atomics == MALL-coherent accesses, NO cache maintenance
__device__ __forceinline__ void h_store_u64(unsigned long long* p, unsigned long long v){
  __hip_atomic_store(p, v, __ATOMIC_RELAXED, __HIP_MEMORY_SCOPE_AGENT);
}
__device__ __forceinline__ unsigned long long h_load_u64(const unsigned long long* p){
  return __hip_atomic_load(p, __ATOMIC_RELAXED, __HIP_MEMORY_SCOPE_AGENT);
}

// ======================= prep kernels =======================
__global__ void k_conv_x0(const float* __restrict__ x, unsigned short* __restrict__ xa){
  const size_t i = (size_t)blockIdx.x*256 + threadIdx.x;
  if (i >= (size_t)T_*B_*KXP) return;
  const int k = (int)(i % KXP);
  const size_t tb = i / KXP;
  xa[i] = f2bf(k < D_ ? x[tb*D_ + k] : 0.f);
}

// Wih -> MFMA B-fragments [2 dir][13 tile][4 gate][2 ch][26 kk][64 lane][8]
__global__ void k_prep_wihR(const float* __restrict__ wf, const float* __restrict__ wb,
                            int mode, unsigned short* __restrict__ dst){
  const size_t i = (size_t)blockIdx.x*256 + threadIdx.x;
  if (i >= WIHR_US8) return;
  const int lane = (int)(i & 63);
  size_t q = i >> 6;
  const int kk = (int)(q % 26); q /= 26;
  const int ch = (int)(q % 2);  q /= 2;
  const int g  = (int)(q % 4);  q /= 4;
  const int tile = (int)(q % 13);
  const int dirx = (int)(q / 13);
  const int c  = tile*32 + ch*16 + (lane & 15);
  const int k0 = kk*32 + (lane >> 4)*8;
  const float* W = dirx ? wb : wf;
  const int stride = mode ? 800 : D_;
  unsigned short v[8];
  #pragma unroll
  for (int e = 0; e < 8; ++e){
    const int k = k0 + e;
    int ks;
    if (mode == 0) ks = (k < D_) ? k : -1;
    else           ks = (k < 400) ? k : ((k >= 416 && k < 816) ? (k - 16) : -1);
    const float x = (c < H_ && ks >= 0) ? W[(size_t)(g*H_ + c)*stride + ks] : 0.f;
    v[e] = f2bf(x);
  }
  *(us8*)(dst + i*8) = *(const us8*)v;
}

// Whh -> B-fragments (R7-verified layout)
__global__ void k_prep_whhR(const float* __restrict__ wf, const float* __restrict__ wb,
                            unsigned short* __restrict__ dst){
  const size_t i = (size_t)blockIdx.x*256 + threadIdx.x;
  if (i >= WHHR_US8) return;
  const int lane = (int)(i & 63);
  size_t q = i >> 6;
  const int kk = (int)(q % 13); q /= 13;
  const int ch = (int)(q % 2);  q /= 2;
  const int w  = (int)(q % 4);  q /= 4;
  const int tile = (int)(q % 13);
  const int dirx = (int)(q / 13);
  const int c  = tile*32 + ch*16 + (lane & 15);
  const int k0 = kk*32 + (lane >> 4)*8;
  const float* W = dirx ? wb : wf;
  unsigned short v[8];
  #pragma unroll
  for (int e = 0; e < 8; ++e){
    const int k = k0 + e;
    const float x = (c < H_ && k < H_) ? W[(size_t)(w*H_ + c)*H_ + k] : 0.f;
    v[e] = f2bf(x);
  }
  *(us8*)(dst + i*8) = *(const us8*)v;
}

__global__ void k_prep_bias(const float* __restrict__ bsf, const float* __restrict__ bsb,
                            float* __restrict__ dst){
  const int n = blockIdx.x*256 + threadIdx.x;
  if (n >= NW) return;
  const int d = n / GP, ng = n % GP, g = ng / HP, r = ng % HP;
  dst[n] = (r < H_) ? (d ? bsb : bsf)[g*H_ + r] : 0.f;
}

// ======================= recurrent (fused; x-work hidden in stall) =======
// grid: 208 blocks = dir(2) x group(8 of 16 batches) x htile(13 of 32 cols)
// DELTA vs R12: per-step schedule reordered so the exchange stall overlaps
// the x-side work: write XS[par] (vx prefetched last step) -> prefetch
// vx(s+1) -> barrier A -> issue h tag-loads -> 52 x-MFMAs (loads in
// flight) -> validate/retry -> HS -> barrier B -> 26 h-MFMAs -> GC ->
// barrier C -> cell -> tagged publish. XS double-buffered. Loop runs the
// closed contiguous active range (same step set/order as R12).
template<bool LAST>
__global__ __launch_bounds__(256, 1) void lstm_rec(
    const unsigned short* __restrict__ xin,    // [T][128][832] bf16
    const unsigned short* __restrict__ wihR,   // Wih fragments
    const unsigned short* __restrict__ whhR,   // Whh fragments
    const float* __restrict__ biasp,           // [NW] f32
    const int* __restrict__ lens,
    unsigned long long* hbt,                   // tagged h (host-zeroed)
    unsigned short* __restrict__ xn,           // [T][128][832] bf16 (or unused)
    float* __restrict__ out)                   // [T][128][800] f32 (or unused)
{
  extern __shared__ char smem[];
  unsigned short* HS = (unsigned short*)smem;                // [16][424]
  unsigned short* XS0 = (unsigned short*)(smem + XS0_OFF);   // [16][840]
  unsigned short* XS1 = (unsigned short*)(smem + XS1_OFF);   // [16][840]
  float* GC = (float*)(smem + GC_OFF);                       // [4][576]

  const int tid = threadIdx.x;
  const int bid = blockIdx.x;
  const int dir  = bid / 104;
  const int rem  = bid % 104;
  const int grp  = rem / NTILES;
  const int tile = rem % NTILES;
  const int l  = tid & 63;
  const int w  = tid >> 6;
  const int lr = l & 15;
  const int lk = l >> 4;
  const int cid = dir*NGRP + grp;

  // Whh B-fragments -> 104 regs (loop-invariant)
  us8 Bf0[13], Bf1[13];
  {
    const unsigned short* bs =
        whhR + ((size_t)((dir*13 + tile)*4 + w)*2*13*64 + l)*8;
    #pragma unroll
    for (int kk = 0; kk < 13; ++kk)
      Bf0[kk] = *(const us8*)(bs + (size_t)kk*512);
    const unsigned short* bs1 = bs + (size_t)13*64*8;
    #pragma unroll
    for (int kk = 0; kk < 13; ++kk)
      Bf1[kk] = *(const us8*)(bs1 + (size_t)kk*512);
  }
  // Wih B-fragments -> 208 regs (loop-invariant)
  us8 Wf0[26], Wf1[26];
  {
    const unsigned short* ws0 =
        wihR + ((size_t)(((dir*13 + tile)*4 + w)*2 + 0)*26*64 + l)*8;
    #pragma unroll
    for (int kk = 0; kk < 26; ++kk)
      Wf0[kk] = *(const us8*)(ws0 + (size_t)kk*512);
    const unsigned short* ws1 = ws0 + (size_t)26*64*8;
    #pragma unroll
    for (int kk = 0; kk < 26; ++kk)
      Wf1[kk] = *(const us8*)(ws1 + (size_t)kk*512);
  }

  const int grp_len = lens[grp*16];          // lens sorted desc -> group max
  const int eb  = tid & 15;                  // elementwise batch
  const int p2  = tid >> 4;                  // col pair within tile
  const int mylen = lens[grp*16 + eb];
  const int c0 = 2*p2, c1 = 2*p2 + 1;
  float b0g[4], b1g[4];
  #pragma unroll
  for (int g = 0; g < 4; ++g){
    b0g[g] = biasp[dir*GP + g*HP + tile*32 + c0];
    b1g[g] = biasp[dir*GP + g*HP + tile*32 + c1];
  }
  float cs0 = 0.f, cs1 = 0.f, hs0 = 0.f, hs1 = 0.f;
  __syncthreads();

  unsigned long long* const myslot =
      hbt + (((size_t)cid*2)*16 + eb)*PAIRS + tile*16 + p2;

  // ---- prologue: load vx for step 0 ----
  unsigned long long vx[13];
  {
    const int t0 = dir ? (grp_len - 1) : 0;
    const unsigned long long* xrow =
        (const unsigned long long*)(xin + ((size_t)t0*B_ + grp*16)*KXP);
    #pragma unroll
    for (int j = 0; j < 13; ++j){
      const int idx = j*256 + tid;
      const int b = idx / 208, qq = idx % 208;
      vx[j] = xrow[(size_t)b*208 + qq];
    }
  }

  for (int ss = 0; ss < grp_len; ++ss){
    const int t = dir ? (grp_len - 1 - ss) : ss;
    unsigned short* XSb = (ss & 1) ? XS1 : XS0;

    // ---- write XS[par] from prefetched vx ----
    #pragma unroll
    for (int j = 0; j < 13; ++j){
      const int idx = j*256 + tid;
      const int b = idx / 208, qq = idx % 208;
      *(unsigned long long*)&XSb[b*XS_STRIDE + qq*4] = vx[j];
    }
    // ---- prefetch vx for step ss+1 (flies across the whole step) ----
    if (ss + 1 < grp_len){
      const int tn = dir ? (grp_len - 2 - ss) : (ss + 1);
      const unsigned long long* xrow =
          (const unsigned long long*)(xin + ((size_t)tn*B_ + grp*16)*KXP);
      #pragma unroll
      for (int j = 0; j < 13; ++j){
        const int idx = j*256 + tid;
        const int b = idx / 208, qq = idx % 208;
        vx[j] = xrow[(size_t)b*208 + qq];
      }
    }
    __syncthreads();                         // A: XS[par] visible

    // ---- issue h tag-loads (in flight during x-MFMAs) ----
    const unsigned rtag = (unsigned)ss;
    const unsigned long long* hb =
        hbt + ((size_t)(cid*2 + (ss & 1))*16)*PAIRS;
    unsigned long long v[13];
    #pragma unroll
    for (int j = 0; j < 13; ++j)
      v[j] = h_load_u64(hb + j*256 + tid);

    // ---- 52 x-side MFMAs (independent of exchange) ----
    f32x4 a0 = (f32x4){0.f,0.f,0.f,0.f}, a1 = (f32x4){0.f,0.f,0.f,0.f};
    {
      const int abx = lr*XS_STRIDE + lk*8;
      #pragma unroll
      for (int kk = 0; kk < 26; ++kk){
        bf16x8 xa = __builtin_bit_cast(bf16x8, *(const us8*)&XSb[abx + kk*32]);
        a0 = __builtin_amdgcn_mfma_f32_16x16x32_bf16(xa, Wf0[kk], a0, 0, 0, 0);
        a1 = __builtin_amdgcn_mfma_f32_16x16x32_bf16(xa, Wf1[kk], a1, 0, 0, 0);
      }
    }
    // ---- validate/retry h; write HS ----
    {
      unsigned stale = 0;
      #pragma unroll
      for (int j = 0; j < 13; ++j)
        if ((unsigned)(v[j] >> 32) != rtag) stale |= 1u << j;
      while (stale){
        const unsigned m = stale;
        #pragma unroll
        for (int j = 0; j < 13; ++j)
          if (m & (1u << j)) v[j] = h_load_u64(hb + j*256 + tid);
        #pragma unroll
        for (int j = 0; j < 13; ++j)
          if ((m & (1u << j)) && (unsigned)(v[j] >> 32) == rtag) stale &= ~(1u << j);
      }
      #pragma unroll
      for (int j = 0; j < 13; ++j){
        const int idx = j*256 + tid;
        const int b = idx / PAIRS, p = idx % PAIRS;
        *(unsigned*)&HS[b*424 + 2*p] = (unsigned)v[j];
      }
    }
    __syncthreads();                         // B: HS visible

    // ---- 26 h-side MFMAs ----
    {
      const int ab = lr*424 + lk*8;
      #pragma unroll
      for (int kk = 0; kk < 13; ++kk){
        bf16x8 av = __builtin_bit_cast(bf16x8, *(const us8*)&HS[ab + kk*32]);
        a0 = __builtin_amdgcn_mfma_f32_16x16x32_bf16(av, Bf0[kk], a0, 0, 0, 0);
        a1 = __builtin_amdgcn_mfma_f32_16x16x32_bf16(av, Bf1[kk], a1, 0, 0, 0);
      }
    }
    // ---- publish gate partials to GC ----
    {
      float* Gw = GC + w * GC_FSTRIDE;
      #pragma unroll
      for (int r = 0; r < 4; ++r){
        Gw[(lk*4 + r)*36 + lr]      = a0[r];
        Gw[(lk*4 + r)*36 + 16 + lr] = a1[r];
      }
    }
    __syncthreads();                         // C: GC visible

    // ---- elementwise LSTM cell ----
    const bool act = t < mylen;
    {
      const float gi0 = GC[0*GC_FSTRIDE + eb*36 + c0] + b0g[0];
      const float gf0 = GC[1*GC_FSTRIDE + eb*36 + c0] + b0g[1];
      const float gg0 = GC[2*GC_FSTRIDE + eb*36 + c0] + b0g[2];
      const float go0 = GC[3*GC_FSTRIDE + eb*36 + c0] + b0g[3];
      const float gi1 = GC[0*GC_FSTRIDE + eb*36 + c1] + b1g[0];
      const float gf1 = GC[1*GC_FSTRIDE + eb*36 + c1] + b1g[1];
      const float gg1 = GC[2*GC_FSTRIDE + eb*36 + c1] + b1g[2];
      const float go1 = GC[3*GC_FSTRIDE + eb*36 + c1] + b1g[3];
      const float cn0 = sigm(gf0)*cs0 + sigm(gi0)*tanh_f(gg0);
      const float hn0 = sigm(go0) * tanh_f(cn0);
      const float cn1 = sigm(gf1)*cs1 + sigm(gi1)*tanh_f(gg1);
      const float hn1 = sigm(go1) * tanh_f(cn1);
      if (act){ cs0 = cn0; hs0 = hn0; cs1 = cn1; hs1 = hn1; }
    }
    // ---- publish tagged h (frozen if masked) into next parity slot ----
    {
      const unsigned hu = (unsigned)f2bf(hs0) | ((unsigned)f2bf(hs1) << 16);
      const unsigned long long hv =
          (unsigned long long)hu | ((unsigned long long)(unsigned)(ss + 1) << 32);
      h_store_u64(myslot + ((size_t)((ss + 1) & 1))*16*PAIRS, hv);
    }
    // ---- layer outputs ----
    if (act){
      const int bg = grp*16 + eb;
      const int hc = tile*32 + c0;
      if constexpr (LAST){
        float* op = out + ((size_t)t*B_ + bg)*800 + dir*H_ + hc;
        if (hc < H_)     op[0] = hs0;
        if (hc + 1 < H_) op[1] = hs1;
      } else {
        const unsigned hu = (unsigned)f2bf(hs0) | ((unsigned)f2bf(hs1) << 16);
        *(unsigned*)(xn + ((size_t)t*B_ + bg)*KXP + (size_t)dir*HP + hc) = hu;
      }
    }
  }
}

// ======================= host side =======================
static void run_all(void* const* din, float* out, char* ws, hipStream_t stream)
{
  const float* x      = (const float*)din[0];
  const int* lens     = (const int*)din[1];
  const float* wihf0  = (const float*)din[2];
  const float* wihf12 = (const float*)din[3];
  const float* whhf   = (const float*)din[4];
  const float* bsf    = (const float*)din[5];
  const float* wihb0  = (const float*)din[6];
  const float* wihb12 = (const float*)din[7];
  const float* whhb   = (const float*)din[8];
  const float* bsb    = (const float*)din[9];

  char* p = ws;
  auto alloc = [&](size_t n){ char* r = p; p += (n + 255) & ~(size_t)255; return r; };
  unsigned short* xA = (unsigned short*)alloc((size_t)T_*B_*KXP*2);
  unsigned short* xB = (unsigned short*)alloc((size_t)T_*B_*KXP*2);
  unsigned short* wihR = (unsigned short*)alloc(WIHR_BYTES);
  unsigned short* whhR = (unsigned short*)alloc(WHHR_BYTES);
  float* biasp       = (float*)alloc((size_t)NW*4);
  unsigned long long* hbt = (unsigned long long*)alloc(HBT_BYTES);

  hipMemsetAsync(out, 0, (size_t)T_*B_*800*4, stream);
  {
    size_t n = (size_t)T_*B_*KXP;
    k_conv_x0<<<dim3((unsigned)((n+255)/256)), dim3(256), 0, stream>>>(x, xA);
  }
  hipFuncSetAttribute(reinterpret_cast<const void*>(&lstm_rec<false>),
                      hipFuncAttributeMaxDynamicSharedMemorySize, LDS_TOTAL);
  hipFuncSetAttribute(reinterpret_cast<const void*>(&lstm_rec<true>),
                      hipFuncAttributeMaxDynamicSharedMemorySize, LDS_TOTAL);

  const unsigned short* xinv[3] = {xA, xB, xA};
  unsigned short* xoutv[3] = {xB, xA, nullptr};

  for (int lyr = 0; lyr < 3; ++lyr){
    const float* wf = (lyr == 0) ? wihf0 : wihf12 + (size_t)(lyr-1)*1600*800;
    const float* wb = (lyr == 0) ? wihb0 : wihb12 + (size_t)(lyr-1)*1600*800;
    {
      size_t n = WIHR_US8;
      k_prep_wihR<<<dim3((unsigned)((n+255)/256)), dim3(256), 0, stream>>>(
          wf, wb, lyr ? 1 : 0, wihR);
    }
    k_prep_bias<<<dim3((NW+255)/256), dim3(256), 0, stream>>>(
        bsf + (size_t)lyr*1600, bsb + (size_t)lyr*1600, biasp);
    {
      size_t n = WHHR_US8;
      k_prep_whhR<<<dim3((unsigned)((n+255)/256)), dim3(256), 0, stream>>>(
          whhf + (size_t)lyr*1600*400, whhb + (size_t)lyr*1600*400, whhR);
    }
    hipMemsetAsync(hbt, 0, HBT_BYTES, stream);

    if (lyr < 2)
      lstm_rec<false><<<dim3(REC_BLOCKS), dim3(256), LDS_TOTAL, stream>>>(
          xinv[lyr], wihR, whhR, biasp, lens, hbt, xoutv[lyr], out);
    else
      lstm_rec<true><<<dim3(REC_BLOCKS), dim3(256), LDS_TOTAL, stream>>>(
          xinv[lyr], wihR, whhR, biasp, lens, hbt, nullptr, out);
  }
}

extern "C" void kernel_launch(void* const* d_in, const int* in_sizes, int n_in,
                              void* d_out, int out_size, void* d_ws, size_t ws_size,
                              hipStream_t stream)
{
  (void)in_sizes; (void)n_in; (void)out_size;
  auto align = [](size_t n){ return (n + 255) & ~(size_t)255; };
  const size_t need =
      align((size_t)T_*B_*KXP*2) * 2 +
      align(WIHR_BYTES) +
      align(WHHR_BYTES) +
      align((size_t)NW*4) +
      align(HBT_BYTES);

  if (ws_size >= need)
    run_all(d_in, (float*)d_out, (char*)d_ws, stream);
  else
    hipMemsetAsync(d_out, 0, (size_t)T_*B_*800*4, stream);
}